// Round 6
// baseline (2889.100 us; speedup 1.0000x reference)
//
#include <hip/hip_runtime.h>

#define NN 50000
#define NE 200000
#define HD 128

typedef unsigned short us4 __attribute__((ext_vector_type(4)));
typedef unsigned short us8 __attribute__((ext_vector_type(8)));
typedef short s8 __attribute__((ext_vector_type(8)));
typedef float f4 __attribute__((ext_vector_type(4)));

#define SA 136    // bf16 LDS k-stride for K=128 (+8 pad) -> 272B rows (17x16B)
#define SA32 40   // bf16 LDS k-stride for K=32 (+8 pad)  -> 80B rows
#define SC2 68    // fp32 LDS dump col-stride for 64-col half (+4 pad)

__device__ __forceinline__ float b2f(unsigned short u) {
    union { unsigned i; float f; } v; v.i = ((unsigned)u) << 16; return v.f;
}
__device__ __forceinline__ unsigned short f2b(float x) {
    union { float f; unsigned i; } v; v.f = x;
    unsigned r = v.i + 0x7fffu + ((v.i >> 16) & 1u);
    return (unsigned short)(r >> 16);
}
struct hl2 { short hi, lo; };
__device__ __forceinline__ hl2 split2(float x) {
    unsigned short h = f2b(x);
    hl2 r;
    r.hi = (short)h;
    r.lo = (short)f2b(x - b2f(h));
    return r;
}

// ---------------------------------------------------------------------------
// zero / utility
// ---------------------------------------------------------------------------
__global__ __launch_bounds__(256) void zero4_k(float4* __restrict__ p, long n4) {
    long i = (long)blockIdx.x * 256 + threadIdx.x;
    if (i < n4) p[i] = float4{0.f, 0.f, 0.f, 0.f};
}
__global__ __launch_bounds__(256) void zeroi_k(int* __restrict__ p, int n) {
    int i = blockIdx.x * 256 + threadIdx.x;
    if (i < n) p[i] = 0;
}
__global__ __launch_bounds__(256) void zerof_k(float* __restrict__ p, long n) {
    long i = (long)blockIdx.x * 256 + threadIdx.x;
    if (i < n) p[i] = 0.f;
}

// ---------------------------------------------------------------------------
// counting-sort prologue (proven)
// ---------------------------------------------------------------------------
__global__ __launch_bounds__(256) void hist_k(const int* __restrict__ dst, int* __restrict__ cnt) {
    int i = blockIdx.x * 256 + threadIdx.x;
    if (i < NE) atomicAdd(&cnt[dst[i]], 1);
}
__global__ __launch_bounds__(256) void scan1_k(const int* __restrict__ cnt, int* __restrict__ bsum) {
    __shared__ int sc[256];
    int i = blockIdx.x * 256 + threadIdx.x;
    sc[threadIdx.x] = (i < NN) ? cnt[i] : 0;
    __syncthreads();
    for (int off = 128; off > 0; off >>= 1) {
        if (threadIdx.x < off) sc[threadIdx.x] += sc[threadIdx.x + off];
        __syncthreads();
    }
    if (threadIdx.x == 0) bsum[blockIdx.x] = sc[0];
}
__global__ __launch_bounds__(256) void scan2_k(int* __restrict__ bsum, int nb) {
    __shared__ int sc[256];
    int t = threadIdx.x;
    int v = (t < nb) ? bsum[t] : 0;
    sc[t] = v;
    __syncthreads();
    for (int off = 1; off < 256; off <<= 1) {
        int a = (t >= off) ? sc[t - off] : 0;
        __syncthreads();
        sc[t] += a;
        __syncthreads();
    }
    if (t < nb) bsum[t] = sc[t] - v;
}
__global__ __launch_bounds__(256) void scan3_k(const int* __restrict__ cnt, const int* __restrict__ bsum,
                                               int* __restrict__ rp, float* __restrict__ deg) {
    __shared__ int sc[256];
    int t = threadIdx.x;
    int i = blockIdx.x * 256 + t;
    int v = (i < NN) ? cnt[i] : 0;
    sc[t] = v;
    __syncthreads();
    for (int off = 1; off < 256; off <<= 1) {
        int a = (t >= off) ? sc[t - off] : 0;
        __syncthreads();
        sc[t] += a;
        __syncthreads();
    }
    int incl = sc[t];
    if (i < NN) {
        rp[i] = bsum[blockIdx.x] + incl - v;
        deg[i] = (float)v;
        if (i == NN - 1) rp[NN] = bsum[blockIdx.x] + incl;
    }
}
__global__ __launch_bounds__(256) void posbuild_k(const int* __restrict__ src, const int* __restrict__ dst,
                                                  const int* __restrict__ rp, int* __restrict__ cur,
                                                  int* __restrict__ pos, int* __restrict__ srcS,
                                                  int* __restrict__ dstS) {
    int i = blockIdx.x * 256 + threadIdx.x;
    if (i >= NE) return;
    int d = dst[i];
    int p = rp[d] + atomicAdd(&cur[d], 1);
    pos[i] = p;
    srcS[p] = src[i];
    dstS[p] = d;
}

// ---------------------------------------------------------------------------
// weight prep
// ---------------------------------------------------------------------------
// W2u = W2 @ uW1b (fp32), b2u = b2 @ uW1b
__global__ __launch_bounds__(256) void mini_k(const float* __restrict__ W2m, const float* __restrict__ uW1b,
                                              const float* __restrict__ b2m,
                                              float* __restrict__ W2u, float* __restrict__ b2u) {
    int r = blockIdx.x * 16 + (threadIdx.x >> 4);
    int c0 = (threadIdx.x & 15) * 8;
    float a[8] = {};
    for (int k = 0; k < HD; ++k) {
        float w = W2m[r * HD + k];
        const float* u = uW1b + k * HD + c0;
        float4 u0 = *(const float4*)u, u1 = *(const float4*)(u + 4);
        a[0] = fmaf(w, u0.x, a[0]); a[1] = fmaf(w, u0.y, a[1]);
        a[2] = fmaf(w, u0.z, a[2]); a[3] = fmaf(w, u0.w, a[3]);
        a[4] = fmaf(w, u1.x, a[4]); a[5] = fmaf(w, u1.y, a[5]);
        a[6] = fmaf(w, u1.z, a[6]); a[7] = fmaf(w, u1.w, a[7]);
    }
    *(float4*)(W2u + r * HD + c0)     = float4{a[0], a[1], a[2], a[3]};
    *(float4*)(W2u + r * HD + c0 + 4) = float4{a[4], a[5], a[6], a[7]};
    if (blockIdx.x == 0 && threadIdx.x < 16) {
        int cc = threadIdx.x * 8;
        float b[8] = {};
        for (int k = 0; k < HD; ++k) {
            float w = b2m[k];
            const float* u = uW1b + k * HD + cc;
            float4 u0 = *(const float4*)u, u1 = *(const float4*)(u + 4);
            b[0] = fmaf(w, u0.x, b[0]); b[1] = fmaf(w, u0.y, b[1]);
            b[2] = fmaf(w, u0.z, b[2]); b[3] = fmaf(w, u0.w, b[3]);
            b[4] = fmaf(w, u1.x, b[4]); b[5] = fmaf(w, u1.y, b[5]);
            b[6] = fmaf(w, u1.z, b[6]); b[7] = fmaf(w, u1.w, b[7]);
        }
        *(float4*)(b2u + cc)     = float4{b[0], b[1], b[2], b[3]};
        *(float4*)(b2u + cc + 4) = float4{b[4], b[5], b[6], b[7]};
    }
}
// 6 matrices [128k][128n] per layer -> transposed [n][k] bf16 hi/lo pairs.
// per matrix m: hi at m*32768, lo at m*32768+16384. m: 0 W1a,1 W1b,2 W1c,3 uW1a,4 uW2,5 W2u
__global__ __launch_bounds__(256) void wtL_k(const float* __restrict__ msgW1, const float* __restrict__ updW1,
                                             const float* __restrict__ updW2, const float* __restrict__ W2uF,
                                             unsigned short* __restrict__ dst) {
    int idx = blockIdx.x * 256 + threadIdx.x;   // 384 blocks = 98304 = 6*16384
    int m = idx >> 14;
    int r = idx & 16383;
    int n = r >> 7, k = r & 127;
    float v;
    switch (m) {
        case 0: v = msgW1[(long)k * HD + n]; break;
        case 1: v = msgW1[(long)(128 + k) * HD + n]; break;
        case 2: v = msgW1[(long)(256 + k) * HD + n]; break;
        case 3: v = updW1[(long)k * HD + n]; break;
        case 4: v = updW2[(long)k * HD + n]; break;
        default: v = W2uF[(long)k * HD + n]; break;
    }
    hl2 p = split2(v);
    dst[(long)m * 32768 + n * HD + k] = (unsigned short)p.hi;
    dst[(long)m * 32768 + 16384 + n * HD + k] = (unsigned short)p.lo;
}
// encoder weights, transposed bf16 hi/lo:
// nW1 [0,8192): hi[0,4096) lo[4096,8192)  ([128n][32k], k>=9 zero)
// nW2 [8192,40960): hi 16384 + lo 16384
// eW1 [40960,49152): hi/lo 4096 each (k>=10 zero)
// eW2 [49152,81920): hi/lo 16384 each
__global__ __launch_bounds__(256) void wtE_k(const float* __restrict__ nW1, const float* __restrict__ nW2,
                                             const float* __restrict__ eW1, const float* __restrict__ eW2,
                                             unsigned short* __restrict__ dst) {
    int idx = blockIdx.x * 256 + threadIdx.x;   // 160 blocks = 40960
    float v; long off; int pos, sz;
    if (idx < 4096) {
        int n = idx >> 5, k = idx & 31;
        v = (k < 9) ? nW1[k * HD + n] : 0.f; off = 0; pos = idx; sz = 4096;
    } else if (idx < 20480) {
        int r = idx - 4096; int n = r >> 7, k = r & 127;
        v = nW2[k * HD + n]; off = 8192; pos = r; sz = 16384;
    } else if (idx < 24576) {
        int r = idx - 20480; int n = r >> 5, k = r & 31;
        v = (k < 10) ? eW1[k * HD + n] : 0.f; off = 40960; pos = r; sz = 4096;
    } else {
        int r = idx - 24576; int n = r >> 7, k = r & 127;
        v = eW2[k * HD + n]; off = 49152; pos = r; sz = 16384;
    }
    hl2 p = split2(v);
    dst[off + pos] = (unsigned short)p.hi;
    dst[off + sz + pos] = (unsigned short)p.lo;
}

// ---------------------------------------------------------------------------
// MFMA helpers. 256 threads = 4 waves; wave w owns rows w*16..+15 of 64-row tile.
// A in LDS bf16 [row][k] (hi tile + optional lo tile). B read from GLOBAL
// (weights tiny, L2-resident, shared by all blocks), layout [n][k] bf16.
// ---------------------------------------------------------------------------
__device__ __forceinline__ void stageA_f32_split(short* __restrict__ At, short* __restrict__ Al,
                                                 const float* __restrict__ A, int bm, int M, int tid) {
#pragma unroll
    for (int t = 0; t < 4; ++t) {
        int c = tid + t * 256;
        int row = c >> 4, k8 = (c & 15) * 8;
        int gr = bm + row;
        s8 vh = (s8)0, vl = (s8)0;
        if (gr < M) {
            const float* p = A + (long)gr * HD + k8;
            f4 a = *(const f4*)p, b = *(const f4*)(p + 4);
#pragma unroll
            for (int i = 0; i < 4; ++i) {
                hl2 pa = split2(a[i]);
                hl2 pb = split2(b[i]);
                vh[i] = pa.hi; vl[i] = pa.lo;
                vh[4 + i] = pb.hi; vl[4 + i] = pb.lo;
            }
        }
        *(s8*)(At + row * SA + k8) = vh;
        *(s8*)(Al + row * SA + k8) = vl;
    }
}
__device__ __forceinline__ void stageA_b16(short* __restrict__ At, const unsigned short* __restrict__ A,
                                           int bm, int M, int tid) {
#pragma unroll
    for (int t = 0; t < 4; ++t) {
        int c = tid + t * 256;
        int row = c >> 4, k8 = (c & 15) * 8;
        int gr = bm + row;
        s8 v = (s8)0;
        if (gr < M) v = *(const s8*)(A + (long)gr * HD + k8);
        *(s8*)(At + row * SA + k8) = v;
    }
}
// one pass: acc[c] += Arow @ Wg[cols c*16..]; Wg global [n][sw k-stride]
__device__ __forceinline__ void mfma_pass(f4 acc[8], const short* __restrict__ Arow, int sa,
                                          const unsigned short* __restrict__ Wg, int sw, int nk, int lane) {
    const int r = lane & 15, q8 = (lane >> 4) * 8;
#pragma unroll
    for (int ks = 0; ks < nk; ++ks) {
        s8 a = *(const s8*)(Arow + r * sa + ks * 32 + q8);
#pragma unroll
        for (int c = 0; c < 8; ++c) {
            s8 b = *(const s8*)((const short*)Wg + (long)(c * 16 + r) * sw + ks * 32 + q8);
            acc[c] = __builtin_amdgcn_mfma_f32_16x16x32_bf16(a, b, acc[c], 0, 0, 0);
        }
    }
}
// fp32-accurate: Ahi@Whi + Alo@Whi + Ahi@Wlo
__device__ __forceinline__ void mfma3(f4 acc[8], const short* __restrict__ At, const short* __restrict__ Al,
                                      int sa, const unsigned short* __restrict__ Whi,
                                      const unsigned short* __restrict__ Wlo, int sw, int nk, int lane) {
    mfma_pass(acc, At, sa, Whi, sw, nk, lane);
    mfma_pass(acc, Al, sa, Whi, sw, nk, lane);
    mfma_pass(acc, At, sa, Wlo, sw, nk, lane);
}
// dump one 64-col half (cols half*64..+63) of C into Cd[64][SC2]
__device__ __forceinline__ void dumpC_half(float* __restrict__ Cd, const f4 acc[8], int half, int w, int lane) {
    const int col = lane & 15, rq = (lane >> 4) * 4;
#pragma unroll
    for (int c = 0; c < 4; ++c)
#pragma unroll
        for (int r = 0; r < 4; ++r)
            Cd[(w * 16 + rq + r) * SC2 + c * 16 + col] = acc[half * 4 + c][r];
}
#define ACC_ZERO(acc) { f4 z_ = {0.f, 0.f, 0.f, 0.f}; for (int c_ = 0; c_ < 8; ++c_) acc[c_] = z_; }

// ---------------------------------------------------------------------------
// dual GEMM: Hs = h@W1a, Hd = h@W1b (bf16 out), shared split-A stage
// ---------------------------------------------------------------------------
__global__ __launch_bounds__(256) void dual_k(const float* __restrict__ h,
                                              const unsigned short* __restrict__ W1aT,
                                              const unsigned short* __restrict__ W1bT,
                                              unsigned short* __restrict__ Hs, unsigned short* __restrict__ Hd,
                                              int M) {
    __shared__ __align__(16) short At[64 * SA];
    __shared__ __align__(16) short Al[64 * SA];
    __shared__ __align__(16) float Cd[64 * SC2];
    const int tid = threadIdx.x, lane = tid & 63, w = tid >> 6, tx = tid & 15, ty = tid >> 4;
    const int bm = blockIdx.x * 64;
    stageA_f32_split(At, Al, h, bm, M, tid);
    __syncthreads();
    const short* Ar = At + (w * 16) * SA;
    const short* Alr = Al + (w * 16) * SA;
    f4 acc[8]; ACC_ZERO(acc);
    mfma3(acc, Ar, Alr, SA, W1aT, W1aT + 16384, HD, 4, lane);
#pragma unroll
    for (int half = 0; half < 2; ++half) {
        __syncthreads();
        dumpC_half(Cd, acc, half, w, lane);
        __syncthreads();
        int c4 = half * 64 + tx * 4;
#pragma unroll
        for (int i = 0; i < 4; ++i) {
            int row = ty * 4 + i, gr = bm + row;
            if (gr >= M) continue;
            f4 v = *(const f4*)(Cd + row * SC2 + tx * 4);
            us4 o;
#pragma unroll
            for (int j = 0; j < 4; ++j) o[j] = f2b(v[j]);
            *(us4*)(Hs + (long)gr * HD + c4) = o;
        }
    }
    ACC_ZERO(acc);
    mfma3(acc, Ar, Alr, SA, W1bT, W1bT + 16384, HD, 4, lane);
#pragma unroll
    for (int half = 0; half < 2; ++half) {
        __syncthreads();
        dumpC_half(Cd, acc, half, w, lane);
        __syncthreads();
        int c4 = half * 64 + tx * 4;
#pragma unroll
        for (int i = 0; i < 4; ++i) {
            int row = ty * 4 + i, gr = bm + row;
            if (gr >= M) continue;
            f4 v = *(const f4*)(Cd + row * SC2 + tx * 4);
            us4 o;
#pragma unroll
            for (int j = 0; j < 4; ++j) o[j] = f2b(v[j]);
            *(us4*)(Hd + (long)gr * HD + c4) = o;
        }
    }
}

// ---------------------------------------------------------------------------
// edge: P = relu(eS@W1c + b1 + Hs[src] + Hd[dst]); S[dst] += P
// eS is exact bf16 (lo==0) -> 2-pass. dst-sorted, run-merged atomics.
// ---------------------------------------------------------------------------
__global__ __launch_bounds__(256) void edge_k(const unsigned short* __restrict__ eS,
                                              const unsigned short* __restrict__ Hs,
                                              const unsigned short* __restrict__ Hd,
                                              const int* __restrict__ srcS, const int* __restrict__ dstS,
                                              const unsigned short* __restrict__ W1cT,
                                              const float* __restrict__ b1, float* __restrict__ S) {
    __shared__ __align__(16) short At[64 * SA];
    __shared__ __align__(16) float Cd[64 * SC2];
    const int tid = threadIdx.x, lane = tid & 63, w = tid >> 6, tx = tid & 15, ty = tid >> 4;
    const int bm = blockIdx.x * 64;
    stageA_b16(At, eS, bm, NE, tid);
    __syncthreads();
    const short* Ar = At + (w * 16) * SA;
    f4 acc[8]; ACC_ZERO(acc);
    mfma_pass(acc, Ar, SA, W1cT, HD, 4, lane);
    mfma_pass(acc, Ar, SA, W1cT + 16384, HD, 4, lane);
#pragma unroll
    for (int half = 0; half < 2; ++half) {
        __syncthreads();
        dumpC_half(Cd, acc, half, w, lane);
        __syncthreads();
        int c4 = half * 64 + tx * 4;
        f4 bv = *(const f4*)(b1 + c4);
        float run[4];
        int rd = -1;
#pragma unroll
        for (int i = 0; i < 4; ++i) {
            int row = ty * 4 + i, edge = bm + row;
            int s = srcS[edge], d = dstS[edge];
            us4 hs = *(const us4*)(Hs + (long)s * HD + c4);
            us4 hd = *(const us4*)(Hd + (long)d * HD + c4);
            f4 cv = *(const f4*)(Cd + row * SC2 + tx * 4);
            float v[4];
#pragma unroll
            for (int j = 0; j < 4; ++j)
                v[j] = fmaxf(cv[j] + bv[j] + b2f(hs[j]) + b2f(hd[j]), 0.f);
            if (d == rd) {
#pragma unroll
                for (int j = 0; j < 4; ++j) run[j] += v[j];
            } else {
                if (rd >= 0) {
#pragma unroll
                    for (int j = 0; j < 4; ++j) atomicAdd(&S[(long)rd * HD + c4 + j], run[j]);
                }
                rd = d;
#pragma unroll
                for (int j = 0; j < 4; ++j) run[j] = v[j];
            }
        }
#pragma unroll
        for (int j = 0; j < 4; ++j) atomicAdd(&S[(long)rd * HD + c4 + j], run[j]);
    }
}

// ---------------------------------------------------------------------------
// update: T = relu(h@uW1a + S@W2u + deg*b2u + ub1);  h += T@uW2 + ub2
// all GEMMs split-precision (3-pass); T written hi/lo into At/Al
// ---------------------------------------------------------------------------
__global__ __launch_bounds__(256) void upd_k(float* __restrict__ h, const float* __restrict__ S,
                                             const unsigned short* __restrict__ uW1aT,
                                             const unsigned short* __restrict__ W2uT,
                                             const float* __restrict__ ub1, const float* __restrict__ b2u,
                                             const float* __restrict__ deg,
                                             const unsigned short* __restrict__ uW2T,
                                             const float* __restrict__ ub2, int M) {
    __shared__ __align__(16) short At[64 * SA];
    __shared__ __align__(16) short Al[64 * SA];
    __shared__ __align__(16) float Cd[64 * SC2];
    const int tid = threadIdx.x, lane = tid & 63, w = tid >> 6, tx = tid & 15, ty = tid >> 4;
    const int bm = blockIdx.x * 64;
    const short* Ar = At + (w * 16) * SA;
    const short* Alr = Al + (w * 16) * SA;
    f4 acc[8]; ACC_ZERO(acc);
    stageA_f32_split(At, Al, h, bm, M, tid);
    __syncthreads();
    mfma3(acc, Ar, Alr, SA, uW1aT, uW1aT + 16384, HD, 4, lane);
    __syncthreads();
    stageA_f32_split(At, Al, S, bm, M, tid);
    __syncthreads();
    mfma3(acc, Ar, Alr, SA, W2uT, W2uT + 16384, HD, 4, lane);
    __syncthreads();
    // T = relu(acc + ub1 + deg*b2u) -> At/Al (hi/lo, C-layout scalar stores)
    {
        const int col0 = lane & 15, rq = (lane >> 4) * 4;
        float u1[8], u2[8], dg[4];
#pragma unroll
        for (int c = 0; c < 8; ++c) { u1[c] = ub1[c * 16 + col0]; u2[c] = b2u[c * 16 + col0]; }
#pragma unroll
        for (int r = 0; r < 4; ++r) { int gr = bm + w * 16 + rq + r; dg[r] = (gr < M) ? deg[gr] : 0.f; }
#pragma unroll
        for (int c = 0; c < 8; ++c)
#pragma unroll
            for (int r = 0; r < 4; ++r) {
                float p = fmaxf(acc[c][r] + u1[c] + dg[r] * u2[c], 0.f);
                hl2 pp = split2(p);
                int off = (w * 16 + rq + r) * SA + c * 16 + col0;
                At[off] = pp.hi;
                Al[off] = pp.lo;
            }
    }
    __syncthreads();
    ACC_ZERO(acc);
    mfma3(acc, Ar, Alr, SA, uW2T, uW2T + 16384, HD, 4, lane);
#pragma unroll
    for (int half = 0; half < 2; ++half) {
        __syncthreads();
        dumpC_half(Cd, acc, half, w, lane);
        __syncthreads();
        int c4 = half * 64 + tx * 4;
        f4 u0 = *(const f4*)(ub2 + c4);
#pragma unroll
        for (int i = 0; i < 4; ++i) {
            int row = ty * 4 + i, gr = bm + row;
            if (gr >= M) continue;
            float* hp = h + (long)gr * HD + c4;
            f4 a = *(f4*)hp;
            f4 cv = *(const f4*)(Cd + row * SC2 + tx * 4);
#pragma unroll
            for (int j = 0; j < 4; ++j) a[j] += cv[j] + u0[j];
            *(f4*)hp = a;
        }
    }
}

// ---------------------------------------------------------------------------
// fused 2-layer encoder (split-precision MFMA). SCAT: bf16 scatter via pos.
// W1T layout [128n][32k], lo at +4096; W2T [128n][128k], lo at +16384.
// ---------------------------------------------------------------------------
template<bool SCAT>
__global__ __launch_bounds__(256) void enc_k(const float* __restrict__ A, int KIN,
                                             const unsigned short* __restrict__ W1T, const float* __restrict__ b1,
                                             const unsigned short* __restrict__ W2T, const float* __restrict__ b2,
                                             float* __restrict__ outF, unsigned short* __restrict__ outB,
                                             const int* __restrict__ pos, int M) {
    __shared__ __align__(16) short At[64 * SA];
    __shared__ __align__(16) short Al[64 * SA];
    __shared__ __align__(16) float Cd[64 * SC2];
    const int tid = threadIdx.x, lane = tid & 63, w = tid >> 6, tx = tid & 15, ty = tid >> 4;
    const int bm = blockIdx.x * 64;
    // phase A: stage [64][32] hi/lo from A[M][KIN], zero-padded
    {
        int row = tid >> 2, k8 = (tid & 3) * 8;
        int gr = bm + row;
        s8 vh = (s8)0, vl = (s8)0;
        if (gr < M) {
#pragma unroll
            for (int i = 0; i < 8; ++i) {
                int k = k8 + i;
                if (k < KIN) {
                    hl2 p = split2(A[(long)gr * KIN + k]);
                    vh[i] = p.hi; vl[i] = p.lo;
                }
            }
        }
        *(s8*)(At + row * SA32 + k8) = vh;
        *(s8*)(Al + row * SA32 + k8) = vl;
    }
    __syncthreads();
    f4 acc[8]; ACC_ZERO(acc);
    mfma3(acc, At + (w * 16) * SA32, Al + (w * 16) * SA32, SA32, W1T, W1T + 4096, 32, 1, lane);
    __syncthreads();
    // P = relu(acc + b1) -> At/Al (hi/lo, K=128 layout)
    {
        const int col0 = lane & 15, rq = (lane >> 4) * 4;
        float bb[8];
#pragma unroll
        for (int c = 0; c < 8; ++c) bb[c] = b1[c * 16 + col0];
#pragma unroll
        for (int c = 0; c < 8; ++c)
#pragma unroll
            for (int r = 0; r < 4; ++r) {
                float p = fmaxf(acc[c][r] + bb[c], 0.f);
                hl2 pp = split2(p);
                int off = (w * 16 + rq + r) * SA + c * 16 + col0;
                At[off] = pp.hi;
                Al[off] = pp.lo;
            }
    }
    __syncthreads();
    ACC_ZERO(acc);
    mfma3(acc, At + (w * 16) * SA, Al + (w * 16) * SA, SA, W2T, W2T + 16384, HD, 4, lane);
#pragma unroll
    for (int half = 0; half < 2; ++half) {
        __syncthreads();
        dumpC_half(Cd, acc, half, w, lane);
        __syncthreads();
        int c4 = half * 64 + tx * 4;
        f4 bv = *(const f4*)(b2 + c4);
#pragma unroll
        for (int i = 0; i < 4; ++i) {
            int row = ty * 4 + i, gr = bm + row;
            if (gr >= M) continue;
            f4 cv = *(const f4*)(Cd + row * SC2 + tx * 4);
            if constexpr (SCAT) {
                int p = pos[gr];
                us4 o;
#pragma unroll
                for (int j = 0; j < 4; ++j) o[j] = f2b(cv[j] + bv[j]);
                *(us4*)(outB + (long)p * HD + c4) = o;
            } else {
                f4 o;
#pragma unroll
                for (int j = 0; j < 4; ++j) o[j] = cv[j] + bv[j];
                *(f4*)(outF + (long)gr * HD + c4) = o;
            }
        }
    }
}

// ---------------------------------------------------------------------------
// fused decoder (VALU, known-correct fp32)
// ---------------------------------------------------------------------------
__global__ __launch_bounds__(256) void dec_k(
    const float* __restrict__ h,
    const float* __restrict__ W1, const float* __restrict__ b1,
    const float* __restrict__ W2, const float* __restrict__ b2,
    const float* __restrict__ W3, const float* __restrict__ b3,
    const float* __restrict__ bc_disp, const float* __restrict__ bc_rot,
    float* __restrict__ outp, int M)
{
    __shared__ float As[64][33];
    __shared__ float Ws[32][HD];
    __shared__ float P[64][HD + 1];
    __shared__ float D2[64][65];
    const int tid = threadIdx.x, tx = tid & 15, ty = tid >> 4;
    const int bm = blockIdx.x * 64;
    float acc[4][8] = {};

    for (int kk = 0; kk < HD; kk += 32) {
        int r = tid >> 2, cc0 = (tid & 3) * 8, gr = bm + r;
#pragma unroll
        for (int i = 0; i < 8; ++i)
            As[r][cc0 + i] = (gr < M) ? h[(long)gr * HD + kk + cc0 + i] : 0.f;
        int k = tid >> 3, n0 = (tid & 7) * 16;
#pragma unroll
        for (int i = 0; i < 16; ++i)
            Ws[k][n0 + i] = W1[(kk + k) * HD + n0 + i];
        __syncthreads();
#pragma unroll
        for (int k2 = 0; k2 < 32; ++k2) {
            float a0 = As[ty * 4 + 0][k2], a1 = As[ty * 4 + 1][k2];
            float a2 = As[ty * 4 + 2][k2], a3 = As[ty * 4 + 3][k2];
#pragma unroll
            for (int j = 0; j < 8; ++j) {
                float ww = Ws[k2][tx * 8 + j];
                acc[0][j] = fmaf(a0, ww, acc[0][j]);
                acc[1][j] = fmaf(a1, ww, acc[1][j]);
                acc[2][j] = fmaf(a2, ww, acc[2][j]);
                acc[3][j] = fmaf(a3, ww, acc[3][j]);
            }
        }
        __syncthreads();
    }
#pragma unroll
    for (int i = 0; i < 4; ++i) {
        int row = ty * 4 + i;
#pragma unroll
        for (int j = 0; j < 8; ++j) {
            int col = tx * 8 + j;
            P[row][col] = fmaxf(acc[i][j] + b1[col], 0.f);
        }
    }
    __syncthreads();
    float acc2[4][4] = {};
    for (int kk = 0; kk < HD; kk += 32) {
        int idx = tid * 8;
        int k = idx >> 6, n0 = idx & 63;
#pragma unroll
        for (int i = 0; i < 8; ++i)
            Ws[k][n0 + i] = W2[(kk + k) * 64 + n0 + i];
        __syncthreads();
#pragma unroll
        for (int k2 = 0; k2 < 32; ++k2) {
            float a0 = P[ty * 4 + 0][kk + k2], a1 = P[ty * 4 + 1][kk + k2];
            float a2 = P[ty * 4 + 2][kk + k2], a3 = P[ty * 4 + 3][kk + k2];
#pragma unroll
            for (int j = 0; j < 4; ++j) {
                float ww = Ws[k2][tx * 4 + j];
                acc2[0][j] = fmaf(a0, ww, acc2[0][j]);
                acc2[1][j] = fmaf(a1, ww, acc2[1][j]);
                acc2[2][j] = fmaf(a2, ww, acc2[2][j]);
                acc2[3][j] = fmaf(a3, ww, acc2[3][j]);
            }
        }
        __syncthreads();
    }
#pragma unroll
    for (int i = 0; i < 4; ++i) {
        int row = ty * 4 + i;
#pragma unroll
        for (int j = 0; j < 4; ++j) {
            int col = tx * 4 + j;
            D2[row][col] = fmaxf(acc2[i][j] + b2[col], 0.f);
        }
    }
    __syncthreads();
    if (tid < 64) {
        int gr = bm + tid;
        if (gr < M) {
            float a0 = b3[0], a1 = b3[1], a2 = b3[2];
#pragma unroll
            for (int k = 0; k < 64; ++k) {
                float v = D2[tid][k];
                a0 = fmaf(v, W3[k * 3 + 0], a0);
                a1 = fmaf(v, W3[k * 3 + 1], a1);
                a2 = fmaf(v, W3[k * 3 + 2], a2);
            }
            outp[gr * 3 + 0] = a0 * (1.f - bc_disp[gr * 2 + 0]);
            outp[gr * 3 + 1] = a1 * (1.f - bc_disp[gr * 2 + 1]);
            outp[gr * 3 + 2] = a2 * (1.f - bc_rot[gr]);
        }
    }
}

// ---------------------------------------------------------------------------
extern "C" void kernel_launch(void* const* d_in, const int* in_sizes, int n_in,
                              void* d_out, int out_size, void* d_ws, size_t ws_size,
                              hipStream_t stream)
{
    const float* x        = (const float*)d_in[0];
    const float* eattr    = (const float*)d_in[1];
    const int*   eidx     = (const int*)d_in[2];
    const float* bc_disp  = (const float*)d_in[3];
    const float* bc_rot   = (const float*)d_in[4];
    const float* enc_n_W1 = (const float*)d_in[5];
    const float* enc_n_b1 = (const float*)d_in[6];
    const float* enc_n_W2 = (const float*)d_in[7];
    const float* enc_n_b2 = (const float*)d_in[8];
    const float* enc_e_W1 = (const float*)d_in[9];
    const float* enc_e_b1 = (const float*)d_in[10];
    const float* enc_e_W2 = (const float*)d_in[11];
    const float* enc_e_b2 = (const float*)d_in[12];
    const float* msg_W1   = (const float*)d_in[13];
    const float* msg_b1   = (const float*)d_in[14];
    const float* msg_W2   = (const float*)d_in[15];
    const float* msg_b2   = (const float*)d_in[16];
    const float* upd_W1   = (const float*)d_in[17];
    const float* upd_b1   = (const float*)d_in[18];
    const float* upd_W2   = (const float*)d_in[19];
    const float* upd_b2   = (const float*)d_in[20];
    const float* dec_W1   = (const float*)d_in[21];
    const float* dec_b1   = (const float*)d_in[22];
    const float* dec_W2   = (const float*)d_in[23];
    const float* dec_b2   = (const float*)d_in[24];
    const float* dec_W3   = (const float*)d_in[25];
    const float* dec_b3   = (const float*)d_in[26];

    const int* src = eidx;
    const int* dst = eidx + NE;

    // workspace layout
    char* base = (char*)d_ws;
    float* h  = (float*)base;                                   // NN*HD f32
    float* S  = h + (long)NN * HD;                              // NN*HD f32
    unsigned short* Hs = (unsigned short*)(S + (long)NN * HD);  // NN*HD bf16
    unsigned short* Hd = Hs + (long)NN * HD;                    // NN*HD bf16
    unsigned short* eS = Hd + (long)NN * HD;                    // NE*HD bf16
    float* W2uF = (float*)(eS + (long)NE * HD);                 // 6*128*128 f32
    float* b2uA = W2uF + 6 * HD * HD;                           // 6*128 f32
    unsigned short* WtL = (unsigned short*)(b2uA + 6 * HD);     // 6 layers * 6 mats * 32768 (hi+lo)
    unsigned short* WtE = WtL + 6L * 6 * 32768;                 // 81920 bf16
    float* deg = (float*)(WtE + 81920);                         // NN f32
    int* rowp  = (int*)(deg + NN);                              // NN+1
    int* cnt   = rowp + (NN + 1);                               // NN
    int* posb  = cnt + NN;                                      // NE
    int* srcS  = posb + NE;                                     // NE
    int* dstS  = srcS + NE;                                     // NE
    int* bsum  = dstS + NE;                                     // 256
    size_t need = (size_t)((char*)(bsum + 256) - base);
    if (ws_size < need) {
        zerof_k<<<(unsigned)((out_size + 255) / 256), 256, 0, stream>>>((float*)d_out, out_size);
        return;
    }

    dim3 blk(256);
    const unsigned gN  = (NN + 63) / 64;    // 782
    const unsigned gE  = NE / 64;           // 3125
    const unsigned gNc = (NN + 255) / 256;  // 196
    const unsigned gEc = (NE + 255) / 256;  // 782

    // --- prologue: counting sort of edges by dst ---
    zeroi_k<<<gNc, blk, 0, stream>>>(cnt, NN);
    hist_k<<<gEc, blk, 0, stream>>>(dst, cnt);
    scan1_k<<<gNc, blk, 0, stream>>>(cnt, bsum);
    scan2_k<<<1, blk, 0, stream>>>(bsum, (int)gNc);
    scan3_k<<<gNc, blk, 0, stream>>>(cnt, bsum, rowp, deg);
    zeroi_k<<<gNc, blk, 0, stream>>>(cnt, NN);
    posbuild_k<<<gEc, blk, 0, stream>>>(src, dst, rowp, cnt, posb, srcS, dstS);

    // --- weight prep: fold W2u per layer, then transpose+split everything ---
    for (int l = 0; l < 6; ++l) {
        mini_k<<<8, blk, 0, stream>>>(msg_W2 + (long)l * HD * HD,
                                      upd_W1 + (long)l * 256 * HD + 128 * HD,
                                      msg_b2 + (long)l * HD,
                                      W2uF + (long)l * HD * HD, b2uA + (long)l * HD);
    }
    for (int l = 0; l < 6; ++l) {
        wtL_k<<<384, blk, 0, stream>>>(msg_W1 + (long)l * 384 * HD,
                                       upd_W1 + (long)l * 256 * HD,
                                       upd_W2 + (long)l * HD * HD,
                                       W2uF + (long)l * HD * HD,
                                       WtL + (long)l * 6 * 32768);
    }
    wtE_k<<<160, blk, 0, stream>>>(enc_n_W1, enc_n_W2, enc_e_W1, enc_e_W2, WtE);

    // --- encoders ---
    enc_k<false><<<gN, blk, 0, stream>>>(x, 9, WtE, enc_n_b1, WtE + 8192, enc_n_b2,
                                         h, nullptr, nullptr, NN);
    enc_k<true><<<gE, blk, 0, stream>>>(eattr, 10, WtE + 40960, enc_e_b1, WtE + 49152, enc_e_b2,
                                        nullptr, eS, posb, NE);

    // --- message-passing layers ---
    for (int l = 0; l < 6; ++l) {
        const unsigned short* Wt = WtL + (long)l * 6 * 32768;
        const float* b1  = msg_b1 + (long)l * HD;
        const float* ub1 = upd_b1 + (long)l * HD;
        const float* ub2 = upd_b2 + (long)l * HD;
        const float* b2u = b2uA + (long)l * HD;

        dual_k<<<gN, blk, 0, stream>>>(h, Wt + 0L * 32768, Wt + 1L * 32768, Hs, Hd, NN);
        {
            long n4 = (long)NN * HD / 4;
            zero4_k<<<(unsigned)((n4 + 255) / 256), blk, 0, stream>>>((float4*)S, n4);
        }
        edge_k<<<gE, blk, 0, stream>>>(eS, Hs, Hd, srcS, dstS, Wt + 2L * 32768, b1, S);
        upd_k<<<gN, blk, 0, stream>>>(h, S, Wt + 3L * 32768, Wt + 5L * 32768,
                                      ub1, b2u, deg, Wt + 4L * 32768, ub2, NN);
    }

    // --- decoder ---
    dec_k<<<gN, blk, 0, stream>>>(h, dec_W1, dec_b1, dec_W2, dec_b2, dec_W3, dec_b3,
                                  bc_disp, bc_rot, (float*)d_out, NN);
}

// Round 7
// 2179.425 us; speedup vs baseline: 1.3256x; 1.3256x over previous
//
#include <hip/hip_runtime.h>

#define NN 50000
#define NE 200000
#define HD 128

typedef unsigned short us4 __attribute__((ext_vector_type(4)));
typedef unsigned short us8 __attribute__((ext_vector_type(8)));
typedef short s8 __attribute__((ext_vector_type(8)));
typedef float f4 __attribute__((ext_vector_type(4)));

#define SA 136    // bf16 LDS k-stride for K=128 (+8 pad) -> 272B rows
#define SA32 40   // bf16 LDS k-stride for K=32 (+8 pad)
#define SC2 68    // fp32 LDS dump col-stride for 64-col half (+4 pad)

__device__ __forceinline__ float b2f(unsigned short u) {
    union { unsigned i; float f; } v; v.i = ((unsigned)u) << 16; return v.f;
}
__device__ __forceinline__ unsigned short f2b(float x) {
    union { float f; unsigned i; } v; v.f = x;
    unsigned r = v.i + 0x7fffu + ((v.i >> 16) & 1u);
    return (unsigned short)(r >> 16);
}
struct hl2 { short hi, lo; };
__device__ __forceinline__ hl2 split2(float x) {
    unsigned short h = f2b(x);
    hl2 r;
    r.hi = (short)h;
    r.lo = (short)f2b(x - b2f(h));
    return r;
}

// ---------------------------------------------------------------------------
// zero / utility
// ---------------------------------------------------------------------------
__global__ __launch_bounds__(256) void zeroi_k(int* __restrict__ p, int n) {
    int i = blockIdx.x * 256 + threadIdx.x;
    if (i < n) p[i] = 0;
}
__global__ __launch_bounds__(256) void zerof_k(float* __restrict__ p, long n) {
    long i = (long)blockIdx.x * 256 + threadIdx.x;
    if (i < n) p[i] = 0.f;
}

// ---------------------------------------------------------------------------
// counting-sort prologue (proven)
// ---------------------------------------------------------------------------
__global__ __launch_bounds__(256) void hist_k(const int* __restrict__ dst, int* __restrict__ cnt) {
    int i = blockIdx.x * 256 + threadIdx.x;
    if (i < NE) atomicAdd(&cnt[dst[i]], 1);
}
__global__ __launch_bounds__(256) void scan1_k(const int* __restrict__ cnt, int* __restrict__ bsum) {
    __shared__ int sc[256];
    int i = blockIdx.x * 256 + threadIdx.x;
    sc[threadIdx.x] = (i < NN) ? cnt[i] : 0;
    __syncthreads();
    for (int off = 128; off > 0; off >>= 1) {
        if (threadIdx.x < off) sc[threadIdx.x] += sc[threadIdx.x + off];
        __syncthreads();
    }
    if (threadIdx.x == 0) bsum[blockIdx.x] = sc[0];
}
__global__ __launch_bounds__(256) void scan2_k(int* __restrict__ bsum, int nb) {
    __shared__ int sc[256];
    int t = threadIdx.x;
    int v = (t < nb) ? bsum[t] : 0;
    sc[t] = v;
    __syncthreads();
    for (int off = 1; off < 256; off <<= 1) {
        int a = (t >= off) ? sc[t - off] : 0;
        __syncthreads();
        sc[t] += a;
        __syncthreads();
    }
    if (t < nb) bsum[t] = sc[t] - v;
}
__global__ __launch_bounds__(256) void scan3_k(const int* __restrict__ cnt, const int* __restrict__ bsum,
                                               int* __restrict__ rp, float* __restrict__ deg) {
    __shared__ int sc[256];
    int t = threadIdx.x;
    int i = blockIdx.x * 256 + t;
    int v = (i < NN) ? cnt[i] : 0;
    sc[t] = v;
    __syncthreads();
    for (int off = 1; off < 256; off <<= 1) {
        int a = (t >= off) ? sc[t - off] : 0;
        __syncthreads();
        sc[t] += a;
        __syncthreads();
    }
    int incl = sc[t];
    if (i < NN) {
        rp[i] = bsum[blockIdx.x] + incl - v;
        deg[i] = (float)v;
        if (i == NN - 1) rp[NN] = bsum[blockIdx.x] + incl;
    }
}
__global__ __launch_bounds__(256) void posbuild_k(const int* __restrict__ src, const int* __restrict__ dst,
                                                  const int* __restrict__ rp, int* __restrict__ cur,
                                                  int* __restrict__ pos, int* __restrict__ srcS,
                                                  int* __restrict__ dstS) {
    int i = blockIdx.x * 256 + threadIdx.x;
    if (i >= NE) return;
    int d = dst[i];
    int p = rp[d] + atomicAdd(&cur[d], 1);
    pos[i] = p;
    srcS[p] = src[i];
    dstS[p] = d;
}

// ---------------------------------------------------------------------------
// weight prep
// ---------------------------------------------------------------------------
__global__ __launch_bounds__(256) void mini_k(const float* __restrict__ W2m, const float* __restrict__ uW1b,
                                              const float* __restrict__ b2m,
                                              float* __restrict__ W2u, float* __restrict__ b2u) {
    int r = blockIdx.x * 16 + (threadIdx.x >> 4);
    int c0 = (threadIdx.x & 15) * 8;
    float a[8] = {};
    for (int k = 0; k < HD; ++k) {
        float w = W2m[r * HD + k];
        const float* u = uW1b + k * HD + c0;
        float4 u0 = *(const float4*)u, u1 = *(const float4*)(u + 4);
        a[0] = fmaf(w, u0.x, a[0]); a[1] = fmaf(w, u0.y, a[1]);
        a[2] = fmaf(w, u0.z, a[2]); a[3] = fmaf(w, u0.w, a[3]);
        a[4] = fmaf(w, u1.x, a[4]); a[5] = fmaf(w, u1.y, a[5]);
        a[6] = fmaf(w, u1.z, a[6]); a[7] = fmaf(w, u1.w, a[7]);
    }
    *(float4*)(W2u + r * HD + c0)     = float4{a[0], a[1], a[2], a[3]};
    *(float4*)(W2u + r * HD + c0 + 4) = float4{a[4], a[5], a[6], a[7]};
    if (blockIdx.x == 0 && threadIdx.x < 16) {
        int cc = threadIdx.x * 8;
        float b[8] = {};
        for (int k = 0; k < HD; ++k) {
            float w = b2m[k];
            const float* u = uW1b + k * HD + cc;
            float4 u0 = *(const float4*)u, u1 = *(const float4*)(u + 4);
            b[0] = fmaf(w, u0.x, b[0]); b[1] = fmaf(w, u0.y, b[1]);
            b[2] = fmaf(w, u0.z, b[2]); b[3] = fmaf(w, u0.w, b[3]);
            b[4] = fmaf(w, u1.x, b[4]); b[5] = fmaf(w, u1.y, b[5]);
            b[6] = fmaf(w, u1.z, b[6]); b[7] = fmaf(w, u1.w, b[7]);
        }
        *(float4*)(b2u + cc)     = float4{b[0], b[1], b[2], b[3]};
        *(float4*)(b2u + cc + 4) = float4{b[4], b[5], b[6], b[7]};
    }
}
// 6 matrices [128k][128n] per layer -> transposed [n][k] bf16 hi/lo pairs.
__global__ __launch_bounds__(256) void wtL_k(const float* __restrict__ msgW1, const float* __restrict__ updW1,
                                             const float* __restrict__ updW2, const float* __restrict__ W2uF,
                                             unsigned short* __restrict__ dst) {
    int idx = blockIdx.x * 256 + threadIdx.x;   // 384 blocks = 98304 = 6*16384
    int m = idx >> 14;
    int r = idx & 16383;
    int n = r >> 7, k = r & 127;
    float v;
    switch (m) {
        case 0: v = msgW1[(long)k * HD + n]; break;
        case 1: v = msgW1[(long)(128 + k) * HD + n]; break;
        case 2: v = msgW1[(long)(256 + k) * HD + n]; break;
        case 3: v = updW1[(long)k * HD + n]; break;
        case 4: v = updW2[(long)k * HD + n]; break;
        default: v = W2uF[(long)k * HD + n]; break;
    }
    hl2 p = split2(v);
    dst[(long)m * 32768 + n * HD + k] = (unsigned short)p.hi;
    dst[(long)m * 32768 + 16384 + n * HD + k] = (unsigned short)p.lo;
}
__global__ __launch_bounds__(256) void wtE_k(const float* __restrict__ nW1, const float* __restrict__ nW2,
                                             const float* __restrict__ eW1, const float* __restrict__ eW2,
                                             unsigned short* __restrict__ dst) {
    int idx = blockIdx.x * 256 + threadIdx.x;   // 160 blocks = 40960
    float v; long off; int pos, sz;
    if (idx < 4096) {
        int n = idx >> 5, k = idx & 31;
        v = (k < 9) ? nW1[k * HD + n] : 0.f; off = 0; pos = idx; sz = 4096;
    } else if (idx < 20480) {
        int r = idx - 4096; int n = r >> 7, k = r & 127;
        v = nW2[k * HD + n]; off = 8192; pos = r; sz = 16384;
    } else if (idx < 24576) {
        int r = idx - 20480; int n = r >> 5, k = r & 31;
        v = (k < 10) ? eW1[k * HD + n] : 0.f; off = 40960; pos = r; sz = 4096;
    } else {
        int r = idx - 24576; int n = r >> 7, k = r & 127;
        v = eW2[k * HD + n]; off = 49152; pos = r; sz = 16384;
    }
    hl2 p = split2(v);
    dst[off + pos] = (unsigned short)p.hi;
    dst[off + sz + pos] = (unsigned short)p.lo;
}

// ---------------------------------------------------------------------------
// MFMA helpers. 256 threads = 4 waves; wave w owns rows w*16..+15 of 64-row tile.
// B fragments register-prefetched from GLOBAL (L2-resident weights, [n][k]).
// ---------------------------------------------------------------------------
__device__ __forceinline__ void stageA_f32_split(short* __restrict__ At, short* __restrict__ Al,
                                                 const float* __restrict__ A, int bm, int M, int tid) {
#pragma unroll
    for (int t = 0; t < 4; ++t) {
        int c = tid + t * 256;
        int row = c >> 4, k8 = (c & 15) * 8;
        int gr = bm + row;
        s8 vh = (s8)0, vl = (s8)0;
        if (gr < M) {
            const float* p = A + (long)gr * HD + k8;
            f4 a = *(const f4*)p, b = *(const f4*)(p + 4);
#pragma unroll
            for (int i = 0; i < 4; ++i) {
                hl2 pa = split2(a[i]);
                hl2 pb = split2(b[i]);
                vh[i] = pa.hi; vl[i] = pa.lo;
                vh[4 + i] = pb.hi; vl[4 + i] = pb.lo;
            }
        }
        *(s8*)(At + row * SA + k8) = vh;
        *(s8*)(Al + row * SA + k8) = vl;
    }
}
__device__ __forceinline__ void stageA_b16(short* __restrict__ At, const unsigned short* __restrict__ A,
                                           int bm, int M, int tid) {
#pragma unroll
    for (int t = 0; t < 4; ++t) {
        int c = tid + t * 256;
        int row = c >> 4, k8 = (c & 15) * 8;
        int gr = bm + row;
        s8 v = (s8)0;
        if (gr < M) v = *(const s8*)(A + (long)gr * HD + k8);
        *(s8*)(At + row * SA + k8) = v;
    }
}
// CSR segment-sum stage: At/Al <- hi/lo of sum over Pe rows [rowp[gr],rowp[gr+1])
__device__ __forceinline__ void stage_segsum_split(short* __restrict__ At, short* __restrict__ Al,
                                                   const unsigned short* __restrict__ Pe,
                                                   const int* __restrict__ rowp,
                                                   int bm, int M, int tid) {
#pragma unroll
    for (int t = 0; t < 4; ++t) {
        int c = tid + t * 256;
        int row = c >> 4, k8 = (c & 15) * 8;
        int gr = bm + row;
        float sum[8] = {};
        if (gr < M) {
            int e0 = rowp[gr], e1 = rowp[gr + 1];
            for (int e = e0; e < e1; ++e) {
                us8 v = *(const us8*)(Pe + (long)e * HD + k8);
#pragma unroll
                for (int i = 0; i < 8; ++i) sum[i] += b2f(v[i]);
            }
        }
        s8 vh, vl;
#pragma unroll
        for (int i = 0; i < 8; ++i) {
            hl2 p = split2(sum[i]);
            vh[i] = p.hi; vl[i] = p.lo;
        }
        *(s8*)(At + row * SA + k8) = vh;
        *(s8*)(Al + row * SA + k8) = vl;
    }
}
// 3-pass fp32-accurate GEMM step with B register-prefetch:
// per ks: load bh[8],bl[8] (16 indep loads), then acc += Ah*bh + Al*bh + Ah*bl
__device__ __forceinline__ void mfma3_pf(f4 acc[8], const short* __restrict__ Ah,
                                         const short* __restrict__ Al, int sa,
                                         const unsigned short* __restrict__ Whi,
                                         const unsigned short* __restrict__ Wlo,
                                         int sw, int nk, int lane) {
    const int r = lane & 15, q8 = (lane >> 4) * 8;
#pragma unroll
    for (int ks = 0; ks < nk; ++ks) {
        s8 bh[8], bl[8];
#pragma unroll
        for (int c = 0; c < 8; ++c)
            bh[c] = *(const s8*)((const short*)Whi + (long)(c * 16 + r) * sw + ks * 32 + q8);
#pragma unroll
        for (int c = 0; c < 8; ++c)
            bl[c] = *(const s8*)((const short*)Wlo + (long)(c * 16 + r) * sw + ks * 32 + q8);
        s8 ah = *(const s8*)(Ah + r * sa + ks * 32 + q8);
        s8 al = *(const s8*)(Al + r * sa + ks * 32 + q8);
#pragma unroll
        for (int c = 0; c < 8; ++c) {
            acc[c] = __builtin_amdgcn_mfma_f32_16x16x32_bf16(ah, bh[c], acc[c], 0, 0, 0);
            acc[c] = __builtin_amdgcn_mfma_f32_16x16x32_bf16(al, bh[c], acc[c], 0, 0, 0);
            acc[c] = __builtin_amdgcn_mfma_f32_16x16x32_bf16(ah, bl[c], acc[c], 0, 0, 0);
        }
    }
}
// 2-pass (A exact bf16): acc += A*bh + A*bl
__device__ __forceinline__ void mfmaE_pf(f4 acc[8], const short* __restrict__ Ar, int sa,
                                         const unsigned short* __restrict__ Whi,
                                         const unsigned short* __restrict__ Wlo,
                                         int sw, int nk, int lane) {
    const int r = lane & 15, q8 = (lane >> 4) * 8;
#pragma unroll
    for (int ks = 0; ks < nk; ++ks) {
        s8 bh[8], bl[8];
#pragma unroll
        for (int c = 0; c < 8; ++c)
            bh[c] = *(const s8*)((const short*)Whi + (long)(c * 16 + r) * sw + ks * 32 + q8);
#pragma unroll
        for (int c = 0; c < 8; ++c)
            bl[c] = *(const s8*)((const short*)Wlo + (long)(c * 16 + r) * sw + ks * 32 + q8);
        s8 a = *(const s8*)(Ar + r * sa + ks * 32 + q8);
#pragma unroll
        for (int c = 0; c < 8; ++c) {
            acc[c] = __builtin_amdgcn_mfma_f32_16x16x32_bf16(a, bh[c], acc[c], 0, 0, 0);
            acc[c] = __builtin_amdgcn_mfma_f32_16x16x32_bf16(a, bl[c], acc[c], 0, 0, 0);
        }
    }
}
__device__ __forceinline__ void dumpC_half(float* __restrict__ Cd, const f4 acc[8], int half, int w, int lane) {
    const int col = lane & 15, rq = (lane >> 4) * 4;
#pragma unroll
    for (int c = 0; c < 4; ++c)
#pragma unroll
        for (int r = 0; r < 4; ++r)
            Cd[(w * 16 + rq + r) * SC2 + c * 16 + col] = acc[half * 4 + c][r];
}
#define ACC_ZERO(acc) { f4 z_ = {0.f, 0.f, 0.f, 0.f}; for (int c_ = 0; c_ < 8; ++c_) acc[c_] = z_; }

// ---------------------------------------------------------------------------
// dual GEMM: Hs = h@W1a, Hd = h@W1b (bf16 out), shared split-A stage
// ---------------------------------------------------------------------------
__global__ __launch_bounds__(256) void dual_k(const float* __restrict__ h,
                                              const unsigned short* __restrict__ W1aT,
                                              const unsigned short* __restrict__ W1bT,
                                              unsigned short* __restrict__ Hs, unsigned short* __restrict__ Hd,
                                              int M) {
    __shared__ __align__(16) short At[64 * SA];
    __shared__ __align__(16) short Al[64 * SA];
    __shared__ __align__(16) float Cd[64 * SC2];
    const int tid = threadIdx.x, lane = tid & 63, w = tid >> 6, tx = tid & 15, ty = tid >> 4;
    const int bm = blockIdx.x * 64;
    stageA_f32_split(At, Al, h, bm, M, tid);
    __syncthreads();
    const short* Ar = At + (w * 16) * SA;
    const short* Alr = Al + (w * 16) * SA;
    f4 acc[8]; ACC_ZERO(acc);
    mfma3_pf(acc, Ar, Alr, SA, W1aT, W1aT + 16384, HD, 4, lane);
#pragma unroll
    for (int half = 0; half < 2; ++half) {
        __syncthreads();
        dumpC_half(Cd, acc, half, w, lane);
        __syncthreads();
        int c4 = half * 64 + tx * 4;
#pragma unroll
        for (int i = 0; i < 4; ++i) {
            int row = ty * 4 + i, gr = bm + row;
            if (gr >= M) continue;
            f4 v = *(const f4*)(Cd + row * SC2 + tx * 4);
            us4 o;
#pragma unroll
            for (int j = 0; j < 4; ++j) o[j] = f2b(v[j]);
            *(us4*)(Hs + (long)gr * HD + c4) = o;
        }
    }
    ACC_ZERO(acc);
    mfma3_pf(acc, Ar, Alr, SA, W1bT, W1bT + 16384, HD, 4, lane);
#pragma unroll
    for (int half = 0; half < 2; ++half) {
        __syncthreads();
        dumpC_half(Cd, acc, half, w, lane);
        __syncthreads();
        int c4 = half * 64 + tx * 4;
#pragma unroll
        for (int i = 0; i < 4; ++i) {
            int row = ty * 4 + i, gr = bm + row;
            if (gr >= M) continue;
            f4 v = *(const f4*)(Cd + row * SC2 + tx * 4);
            us4 o;
#pragma unroll
            for (int j = 0; j < 4; ++j) o[j] = f2b(v[j]);
            *(us4*)(Hd + (long)gr * HD + c4) = o;
        }
    }
}

// ---------------------------------------------------------------------------
// edge: Pe[edge] = relu(eS@W1c + b1 + Hs[src] + Hd[dst])  (NO atomics;
// Pe is in dst-sorted order, consumed by upd_k's CSR segment-sum)
// ---------------------------------------------------------------------------
__global__ __launch_bounds__(256) void edge_k(const unsigned short* __restrict__ eS,
                                              const unsigned short* __restrict__ Hs,
                                              const unsigned short* __restrict__ Hd,
                                              const int* __restrict__ srcS, const int* __restrict__ dstS,
                                              const unsigned short* __restrict__ W1cT,
                                              const float* __restrict__ b1,
                                              unsigned short* __restrict__ Pe) {
    __shared__ __align__(16) short At[64 * SA];
    __shared__ __align__(16) float Cd[64 * SC2];
    const int tid = threadIdx.x, lane = tid & 63, w = tid >> 6, tx = tid & 15, ty = tid >> 4;
    const int bm = blockIdx.x * 64;
    stageA_b16(At, eS, bm, NE, tid);
    __syncthreads();
    const short* Ar = At + (w * 16) * SA;
    f4 acc[8]; ACC_ZERO(acc);
    mfmaE_pf(acc, Ar, SA, W1cT, W1cT + 16384, HD, 4, lane);
#pragma unroll
    for (int half = 0; half < 2; ++half) {
        __syncthreads();
        dumpC_half(Cd, acc, half, w, lane);
        __syncthreads();
        int c4 = half * 64 + tx * 4;
        f4 bv = *(const f4*)(b1 + c4);
#pragma unroll
        for (int i = 0; i < 4; ++i) {
            int row = ty * 4 + i, edge = bm + row;
            int s = srcS[edge], d = dstS[edge];
            us4 hs = *(const us4*)(Hs + (long)s * HD + c4);
            us4 hd = *(const us4*)(Hd + (long)d * HD + c4);
            f4 cv = *(const f4*)(Cd + row * SC2 + tx * 4);
            us4 o;
#pragma unroll
            for (int j = 0; j < 4; ++j)
                o[j] = f2b(fmaxf(cv[j] + bv[j] + b2f(hs[j]) + b2f(hd[j]), 0.f));
            *(us4*)(Pe + (long)edge * HD + c4) = o;
        }
    }
}

// ---------------------------------------------------------------------------
// update: S = segsum(Pe); T = relu(h@uW1a + S@W2u + deg*b2u + ub1); h += T@uW2 + ub2
// ---------------------------------------------------------------------------
__global__ __launch_bounds__(256) void upd_k(float* __restrict__ h,
                                             const unsigned short* __restrict__ Pe,
                                             const int* __restrict__ rowp,
                                             const unsigned short* __restrict__ uW1aT,
                                             const unsigned short* __restrict__ W2uT,
                                             const float* __restrict__ ub1, const float* __restrict__ b2u,
                                             const float* __restrict__ deg,
                                             const unsigned short* __restrict__ uW2T,
                                             const float* __restrict__ ub2, int M) {
    __shared__ __align__(16) short At[64 * SA];
    __shared__ __align__(16) short Al[64 * SA];
    __shared__ __align__(16) float Cd[64 * SC2];
    const int tid = threadIdx.x, lane = tid & 63, w = tid >> 6, tx = tid & 15, ty = tid >> 4;
    const int bm = blockIdx.x * 64;
    const short* Ar = At + (w * 16) * SA;
    const short* Alr = Al + (w * 16) * SA;
    f4 acc[8]; ACC_ZERO(acc);
    stageA_f32_split(At, Al, h, bm, M, tid);
    __syncthreads();
    mfma3_pf(acc, Ar, Alr, SA, uW1aT, uW1aT + 16384, HD, 4, lane);
    __syncthreads();
    stage_segsum_split(At, Al, Pe, rowp, bm, M, tid);
    __syncthreads();
    mfma3_pf(acc, Ar, Alr, SA, W2uT, W2uT + 16384, HD, 4, lane);
    __syncthreads();
    // T = relu(acc + ub1 + deg*b2u) -> At/Al
    {
        const int col0 = lane & 15, rq = (lane >> 4) * 4;
        float u1[8], u2[8], dg[4];
#pragma unroll
        for (int c = 0; c < 8; ++c) { u1[c] = ub1[c * 16 + col0]; u2[c] = b2u[c * 16 + col0]; }
#pragma unroll
        for (int r = 0; r < 4; ++r) { int gr = bm + w * 16 + rq + r; dg[r] = (gr < M) ? deg[gr] : 0.f; }
#pragma unroll
        for (int c = 0; c < 8; ++c)
#pragma unroll
            for (int r = 0; r < 4; ++r) {
                float p = fmaxf(acc[c][r] + u1[c] + dg[r] * u2[c], 0.f);
                hl2 pp = split2(p);
                int off = (w * 16 + rq + r) * SA + c * 16 + col0;
                At[off] = pp.hi;
                Al[off] = pp.lo;
            }
    }
    __syncthreads();
    ACC_ZERO(acc);
    mfma3_pf(acc, Ar, Alr, SA, uW2T, uW2T + 16384, HD, 4, lane);
#pragma unroll
    for (int half = 0; half < 2; ++half) {
        __syncthreads();
        dumpC_half(Cd, acc, half, w, lane);
        __syncthreads();
        int c4 = half * 64 + tx * 4;
        f4 u0 = *(const f4*)(ub2 + c4);
#pragma unroll
        for (int i = 0; i < 4; ++i) {
            int row = ty * 4 + i, gr = bm + row;
            if (gr >= M) continue;
            float* hp = h + (long)gr * HD + c4;
            f4 a = *(f4*)hp;
            f4 cv = *(const f4*)(Cd + row * SC2 + tx * 4);
#pragma unroll
            for (int j = 0; j < 4; ++j) a[j] += cv[j] + u0[j];
            *(f4*)hp = a;
        }
    }
}

// ---------------------------------------------------------------------------
// fused 2-layer encoder (split-precision MFMA). SCAT: bf16 scatter via pos.
// ---------------------------------------------------------------------------
template<bool SCAT>
__global__ __launch_bounds__(256) void enc_k(const float* __restrict__ A, int KIN,
                                             const unsigned short* __restrict__ W1T, const float* __restrict__ b1,
                                             const unsigned short* __restrict__ W2T, const float* __restrict__ b2,
                                             float* __restrict__ outF, unsigned short* __restrict__ outB,
                                             const int* __restrict__ pos, int M) {
    __shared__ __align__(16) short At[64 * SA];
    __shared__ __align__(16) short Al[64 * SA];
    __shared__ __align__(16) float Cd[64 * SC2];
    const int tid = threadIdx.x, lane = tid & 63, w = tid >> 6, tx = tid & 15, ty = tid >> 4;
    const int bm = blockIdx.x * 64;
    {
        int row = tid >> 2, k8 = (tid & 3) * 8;
        int gr = bm + row;
        s8 vh = (s8)0, vl = (s8)0;
        if (gr < M) {
#pragma unroll
            for (int i = 0; i < 8; ++i) {
                int k = k8 + i;
                if (k < KIN) {
                    hl2 p = split2(A[(long)gr * KIN + k]);
                    vh[i] = p.hi; vl[i] = p.lo;
                }
            }
        }
        *(s8*)(At + row * SA32 + k8) = vh;
        *(s8*)(Al + row * SA32 + k8) = vl;
    }
    __syncthreads();
    f4 acc[8]; ACC_ZERO(acc);
    mfma3_pf(acc, At + (w * 16) * SA32, Al + (w * 16) * SA32, SA32, W1T, W1T + 4096, 32, 1, lane);
    __syncthreads();
    {
        const int col0 = lane & 15, rq = (lane >> 4) * 4;
        float bb[8];
#pragma unroll
        for (int c = 0; c < 8; ++c) bb[c] = b1[c * 16 + col0];
#pragma unroll
        for (int c = 0; c < 8; ++c)
#pragma unroll
            for (int r = 0; r < 4; ++r) {
                float p = fmaxf(acc[c][r] + bb[c], 0.f);
                hl2 pp = split2(p);
                int off = (w * 16 + rq + r) * SA + c * 16 + col0;
                At[off] = pp.hi;
                Al[off] = pp.lo;
            }
    }
    __syncthreads();
    ACC_ZERO(acc);
    mfma3_pf(acc, At + (w * 16) * SA, Al + (w * 16) * SA, SA, W2T, W2T + 16384, HD, 4, lane);
#pragma unroll
    for (int half = 0; half < 2; ++half) {
        __syncthreads();
        dumpC_half(Cd, acc, half, w, lane);
        __syncthreads();
        int c4 = half * 64 + tx * 4;
        f4 bv = *(const f4*)(b2 + c4);
#pragma unroll
        for (int i = 0; i < 4; ++i) {
            int row = ty * 4 + i, gr = bm + row;
            if (gr >= M) continue;
            f4 cv = *(const f4*)(Cd + row * SC2 + tx * 4);
            if constexpr (SCAT) {
                int p = pos[gr];
                us4 o;
#pragma unroll
                for (int j = 0; j < 4; ++j) o[j] = f2b(cv[j] + bv[j]);
                *(us4*)(outB + (long)p * HD + c4) = o;
            } else {
                f4 o;
#pragma unroll
                for (int j = 0; j < 4; ++j) o[j] = cv[j] + bv[j];
                *(f4*)(outF + (long)gr * HD + c4) = o;
            }
        }
    }
}

// ---------------------------------------------------------------------------
// fused decoder (VALU, known-correct fp32)
// ---------------------------------------------------------------------------
__global__ __launch_bounds__(256) void dec_k(
    const float* __restrict__ h,
    const float* __restrict__ W1, const float* __restrict__ b1,
    const float* __restrict__ W2, const float* __restrict__ b2,
    const float* __restrict__ W3, const float* __restrict__ b3,
    const float* __restrict__ bc_disp, const float* __restrict__ bc_rot,
    float* __restrict__ outp, int M)
{
    __shared__ float As[64][33];
    __shared__ float Ws[32][HD];
    __shared__ float P[64][HD + 1];
    __shared__ float D2[64][65];
    const int tid = threadIdx.x, tx = tid & 15, ty = tid >> 4;
    const int bm = blockIdx.x * 64;
    float acc[4][8] = {};

    for (int kk = 0; kk < HD; kk += 32) {
        int r = tid >> 2, cc0 = (tid & 3) * 8, gr = bm + r;
#pragma unroll
        for (int i = 0; i < 8; ++i)
            As[r][cc0 + i] = (gr < M) ? h[(long)gr * HD + kk + cc0 + i] : 0.f;
        int k = tid >> 3, n0 = (tid & 7) * 16;
#pragma unroll
        for (int i = 0; i < 16; ++i)
            Ws[k][n0 + i] = W1[(kk + k) * HD + n0 + i];
        __syncthreads();
#pragma unroll
        for (int k2 = 0; k2 < 32; ++k2) {
            float a0 = As[ty * 4 + 0][k2], a1 = As[ty * 4 + 1][k2];
            float a2 = As[ty * 4 + 2][k2], a3 = As[ty * 4 + 3][k2];
#pragma unroll
            for (int j = 0; j < 8; ++j) {
                float ww = Ws[k2][tx * 8 + j];
                acc[0][j] = fmaf(a0, ww, acc[0][j]);
                acc[1][j] = fmaf(a1, ww, acc[1][j]);
                acc[2][j] = fmaf(a2, ww, acc[2][j]);
                acc[3][j] = fmaf(a3, ww, acc[3][j]);
            }
        }
        __syncthreads();
    }
#pragma unroll
    for (int i = 0; i < 4; ++i) {
        int row = ty * 4 + i;
#pragma unroll
        for (int j = 0; j < 8; ++j) {
            int col = tx * 8 + j;
            P[row][col] = fmaxf(acc[i][j] + b1[col], 0.f);
        }
    }
    __syncthreads();
    float acc2[4][4] = {};
    for (int kk = 0; kk < HD; kk += 32) {
        int idx = tid * 8;
        int k = idx >> 6, n0 = idx & 63;
#pragma unroll
        for (int i = 0; i < 8; ++i)
            Ws[k][n0 + i] = W2[(kk + k) * 64 + n0 + i];
        __syncthreads();
#pragma unroll
        for (int k2 = 0; k2 < 32; ++k2) {
            float a0 = P[ty * 4 + 0][kk + k2], a1 = P[ty * 4 + 1][kk + k2];
            float a2 = P[ty * 4 + 2][kk + k2], a3 = P[ty * 4 + 3][kk + k2];
#pragma unroll
            for (int j = 0; j < 4; ++j) {
                float ww = Ws[k2][tx * 4 + j];
                acc2[0][j] = fmaf(a0, ww, acc2[0][j]);
                acc2[1][j] = fmaf(a1, ww, acc2[1][j]);
                acc2[2][j] = fmaf(a2, ww, acc2[2][j]);
                acc2[3][j] = fmaf(a3, ww, acc2[3][j]);
            }
        }
        __syncthreads();
    }
#pragma unroll
    for (int i = 0; i < 4; ++i) {
        int row = ty * 4 + i;
#pragma unroll
        for (int j = 0; j < 4; ++j) {
            int col = tx * 4 + j;
            D2[row][col] = fmaxf(acc2[i][j] + b2[col], 0.f);
        }
    }
    __syncthreads();
    if (tid < 64) {
        int gr = bm + tid;
        if (gr < M) {
            float a0 = b3[0], a1 = b3[1], a2 = b3[2];
#pragma unroll
            for (int k = 0; k < 64; ++k) {
                float v = D2[tid][k];
                a0 = fmaf(v, W3[k * 3 + 0], a0);
                a1 = fmaf(v, W3[k * 3 + 1], a1);
                a2 = fmaf(v, W3[k * 3 + 2], a2);
            }
            outp[gr * 3 + 0] = a0 * (1.f - bc_disp[gr * 2 + 0]);
            outp[gr * 3 + 1] = a1 * (1.f - bc_disp[gr * 2 + 1]);
            outp[gr * 3 + 2] = a2 * (1.f - bc_rot[gr]);
        }
    }
}

// ---------------------------------------------------------------------------
extern "C" void kernel_launch(void* const* d_in, const int* in_sizes, int n_in,
                              void* d_out, int out_size, void* d_ws, size_t ws_size,
                              hipStream_t stream)
{
    const float* x        = (const float*)d_in[0];
    const float* eattr    = (const float*)d_in[1];
    const int*   eidx     = (const int*)d_in[2];
    const float* bc_disp  = (const float*)d_in[3];
    const float* bc_rot   = (const float*)d_in[4];
    const float* enc_n_W1 = (const float*)d_in[5];
    const float* enc_n_b1 = (const float*)d_in[6];
    const float* enc_n_W2 = (const float*)d_in[7];
    const float* enc_n_b2 = (const float*)d_in[8];
    const float* enc_e_W1 = (const float*)d_in[9];
    const float* enc_e_b1 = (const float*)d_in[10];
    const float* enc_e_W2 = (const float*)d_in[11];
    const float* enc_e_b2 = (const float*)d_in[12];
    const float* msg_W1   = (const float*)d_in[13];
    const float* msg_b1   = (const float*)d_in[14];
    const float* msg_W2   = (const float*)d_in[15];
    const float* msg_b2   = (const float*)d_in[16];
    const float* upd_W1   = (const float*)d_in[17];
    const float* upd_b1   = (const float*)d_in[18];
    const float* upd_W2   = (const float*)d_in[19];
    const float* upd_b2   = (const float*)d_in[20];
    const float* dec_W1   = (const float*)d_in[21];
    const float* dec_b1   = (const float*)d_in[22];
    const float* dec_W2   = (const float*)d_in[23];
    const float* dec_b2   = (const float*)d_in[24];
    const float* dec_W3   = (const float*)d_in[25];
    const float* dec_b3   = (const float*)d_in[26];

    const int* src = eidx;
    const int* dst = eidx + NE;

    // workspace layout
    char* base = (char*)d_ws;
    float* h  = (float*)base;                                   // NN*HD f32
    unsigned short* Hs = (unsigned short*)(h + (long)NN * HD);  // NN*HD bf16
    unsigned short* Hd = Hs + (long)NN * HD;                    // NN*HD bf16
    unsigned short* eS = Hd + (long)NN * HD;                    // NE*HD bf16
    unsigned short* Pe = eS + (long)NE * HD;                    // NE*HD bf16
    float* W2uF = (float*)(Pe + (long)NE * HD);                 // 6*128*128 f32
    float* b2uA = W2uF + 6 * HD * HD;                           // 6*128 f32
    unsigned short* WtL = (unsigned short*)(b2uA + 6 * HD);     // 6*6*32768 bf16
    unsigned short* WtE = WtL + 6L * 6 * 32768;                 // 81920 bf16
    float* deg = (float*)(WtE + 81920);                         // NN f32
    int* rowp  = (int*)(deg + NN);                              // NN+1
    int* cnt   = rowp + (NN + 1);                               // NN
    int* posb  = cnt + NN;                                      // NE
    int* srcS  = posb + NE;                                     // NE
    int* dstS  = srcS + NE;                                     // NE
    int* bsum  = dstS + NE;                                     // 256
    size_t need = (size_t)((char*)(bsum + 256) - base);
    if (ws_size < need) {
        zerof_k<<<(unsigned)((out_size + 255) / 256), 256, 0, stream>>>((float*)d_out, out_size);
        return;
    }

    dim3 blk(256);
    const unsigned gN  = (NN + 63) / 64;    // 782
    const unsigned gE  = NE / 64;           // 3125
    const unsigned gNc = (NN + 255) / 256;  // 196
    const unsigned gEc = (NE + 255) / 256;  // 782

    // --- prologue: counting sort of edges by dst ---
    zeroi_k<<<gNc, blk, 0, stream>>>(cnt, NN);
    hist_k<<<gEc, blk, 0, stream>>>(dst, cnt);
    scan1_k<<<gNc, blk, 0, stream>>>(cnt, bsum);
    scan2_k<<<1, blk, 0, stream>>>(bsum, (int)gNc);
    scan3_k<<<gNc, blk, 0, stream>>>(cnt, bsum, rowp, deg);
    zeroi_k<<<gNc, blk, 0, stream>>>(cnt, NN);
    posbuild_k<<<gEc, blk, 0, stream>>>(src, dst, rowp, cnt, posb, srcS, dstS);

    // --- weight prep ---
    for (int l = 0; l < 6; ++l) {
        mini_k<<<8, blk, 0, stream>>>(msg_W2 + (long)l * HD * HD,
                                      upd_W1 + (long)l * 256 * HD + 128 * HD,
                                      msg_b2 + (long)l * HD,
                                      W2uF + (long)l * HD * HD, b2uA + (long)l * HD);
    }
    for (int l = 0; l < 6; ++l) {
        wtL_k<<<384, blk, 0, stream>>>(msg_W1 + (long)l * 384 * HD,
                                       upd_W1 + (long)l * 256 * HD,
                                       upd_W2 + (long)l * HD * HD,
                                       W2uF + (long)l * HD * HD,
                                       WtL + (long)l * 6 * 32768);
    }
    wtE_k<<<160, blk, 0, stream>>>(enc_n_W1, enc_n_W2, enc_e_W1, enc_e_W2, WtE);

    // --- encoders ---
    enc_k<false><<<gN, blk, 0, stream>>>(x, 9, WtE, enc_n_b1, WtE + 8192, enc_n_b2,
                                         h, nullptr, nullptr, NN);
    enc_k<true><<<gE, blk, 0, stream>>>(eattr, 10, WtE + 40960, enc_e_b1, WtE + 49152, enc_e_b2,
                                        nullptr, eS, posb, NE);

    // --- message-passing layers ---
    for (int l = 0; l < 6; ++l) {
        const unsigned short* Wt = WtL + (long)l * 6 * 32768;
        const float* b1  = msg_b1 + (long)l * HD;
        const float* ub1 = upd_b1 + (long)l * HD;
        const float* ub2 = upd_b2 + (long)l * HD;
        const float* b2u = b2uA + (long)l * HD;

        dual_k<<<gN, blk, 0, stream>>>(h, Wt + 0L * 32768, Wt + 1L * 32768, Hs, Hd, NN);
        edge_k<<<gE, blk, 0, stream>>>(eS, Hs, Hd, srcS, dstS, Wt + 2L * 32768, b1, Pe);
        upd_k<<<gN, blk, 0, stream>>>(h, Pe, rowp, Wt + 3L * 32768, Wt + 5L * 32768,
                                      ub1, b2u, deg, Wt + 4L * 32768, ub2, NN);
    }

    // --- decoder ---
    dec_k<<<gN, blk, 0, stream>>>(h, dec_W1, dec_b1, dec_W2, dec_b2, dec_W3, dec_b3,
                                  bc_disp, bc_rot, (float*)d_out, NN);
}

// Round 8
// 1126.262 us; speedup vs baseline: 2.5652x; 1.9351x over previous
//
#include <hip/hip_runtime.h>

#define NN 50000
#define NE 200000
#define HD 128

typedef unsigned short us4 __attribute__((ext_vector_type(4)));
typedef unsigned short us8 __attribute__((ext_vector_type(8)));
typedef short s8 __attribute__((ext_vector_type(8)));
typedef float f4 __attribute__((ext_vector_type(4)));

#define SA 136    // bf16 LDS k-stride for K=128 (+8 pad) -> 272B rows
#define SA32 40   // bf16 LDS k-stride for K=32 (+8 pad)
#define SC2 68    // fp32 LDS dump col-stride for 64-col half (+4 pad)

__device__ __forceinline__ float b2f(unsigned short u) {
    union { unsigned i; float f; } v; v.i = ((unsigned)u) << 16; return v.f;
}
__device__ __forceinline__ unsigned short f2b(float x) {
    union { float f; unsigned i; } v; v.f = x;
    unsigned r = v.i + 0x7fffu + ((v.i >> 16) & 1u);
    return (unsigned short)(r >> 16);
}
struct hl2 { short hi, lo; };
__device__ __forceinline__ hl2 split2(float x) {
    unsigned short h = f2b(x);
    hl2 r;
    r.hi = (short)h;
    r.lo = (short)f2b(x - b2f(h));
    return r;
}

// ---------------------------------------------------------------------------
// zero / utility
// ---------------------------------------------------------------------------
__global__ __launch_bounds__(256) void zeroi_k(int* __restrict__ p, int n) {
    int i = blockIdx.x * 256 + threadIdx.x;
    if (i < n) p[i] = 0;
}
__global__ __launch_bounds__(256) void zerof_k(float* __restrict__ p, long n) {
    long i = (long)blockIdx.x * 256 + threadIdx.x;
    if (i < n) p[i] = 0.f;
}

// ---------------------------------------------------------------------------
// counting-sort prologue (proven)
// ---------------------------------------------------------------------------
__global__ __launch_bounds__(256) void hist_k(const int* __restrict__ dst, int* __restrict__ cnt) {
    int i = blockIdx.x * 256 + threadIdx.x;
    if (i < NE) atomicAdd(&cnt[dst[i]], 1);
}
__global__ __launch_bounds__(256) void scan1_k(const int* __restrict__ cnt, int* __restrict__ bsum) {
    __shared__ int sc[256];
    int i = blockIdx.x * 256 + threadIdx.x;
    sc[threadIdx.x] = (i < NN) ? cnt[i] : 0;
    __syncthreads();
    for (int off = 128; off > 0; off >>= 1) {
        if (threadIdx.x < off) sc[threadIdx.x] += sc[threadIdx.x + off];
        __syncthreads();
    }
    if (threadIdx.x == 0) bsum[blockIdx.x] = sc[0];
}
__global__ __launch_bounds__(256) void scan2_k(int* __restrict__ bsum, int nb) {
    __shared__ int sc[256];
    int t = threadIdx.x;
    int v = (t < nb) ? bsum[t] : 0;
    sc[t] = v;
    __syncthreads();
    for (int off = 1; off < 256; off <<= 1) {
        int a = (t >= off) ? sc[t - off] : 0;
        __syncthreads();
        sc[t] += a;
        __syncthreads();
    }
    if (t < nb) bsum[t] = sc[t] - v;
}
__global__ __launch_bounds__(256) void scan3_k(const int* __restrict__ cnt, const int* __restrict__ bsum,
                                               int* __restrict__ rp, float* __restrict__ deg) {
    __shared__ int sc[256];
    int t = threadIdx.x;
    int i = blockIdx.x * 256 + t;
    int v = (i < NN) ? cnt[i] : 0;
    sc[t] = v;
    __syncthreads();
    for (int off = 1; off < 256; off <<= 1) {
        int a = (t >= off) ? sc[t - off] : 0;
        __syncthreads();
        sc[t] += a;
        __syncthreads();
    }
    int incl = sc[t];
    if (i < NN) {
        rp[i] = bsum[blockIdx.x] + incl - v;
        deg[i] = (float)v;
        if (i == NN - 1) rp[NN] = bsum[blockIdx.x] + incl;
    }
}
__global__ __launch_bounds__(256) void posbuild_k(const int* __restrict__ src, const int* __restrict__ dst,
                                                  const int* __restrict__ rp, int* __restrict__ cur,
                                                  int* __restrict__ pos, int* __restrict__ srcS,
                                                  int* __restrict__ dstS) {
    int i = blockIdx.x * 256 + threadIdx.x;
    if (i >= NE) return;
    int d = dst[i];
    int p = rp[d] + atomicAdd(&cur[d], 1);
    pos[i] = p;
    srcS[p] = src[i];
    dstS[p] = d;
}

// ---------------------------------------------------------------------------
// weight prep (unchanged)
// ---------------------------------------------------------------------------
__global__ __launch_bounds__(256) void mini_k(const float* __restrict__ W2m, const float* __restrict__ uW1b,
                                              const float* __restrict__ b2m,
                                              float* __restrict__ W2u, float* __restrict__ b2u) {
    int r = blockIdx.x * 16 + (threadIdx.x >> 4);
    int c0 = (threadIdx.x & 15) * 8;
    float a[8] = {};
    for (int k = 0; k < HD; ++k) {
        float w = W2m[r * HD + k];
        const float* u = uW1b + k * HD + c0;
        float4 u0 = *(const float4*)u, u1 = *(const float4*)(u + 4);
        a[0] = fmaf(w, u0.x, a[0]); a[1] = fmaf(w, u0.y, a[1]);
        a[2] = fmaf(w, u0.z, a[2]); a[3] = fmaf(w, u0.w, a[3]);
        a[4] = fmaf(w, u1.x, a[4]); a[5] = fmaf(w, u1.y, a[5]);
        a[6] = fmaf(w, u1.z, a[6]); a[7] = fmaf(w, u1.w, a[7]);
    }
    *(float4*)(W2u + r * HD + c0)     = float4{a[0], a[1], a[2], a[3]};
    *(float4*)(W2u + r * HD + c0 + 4) = float4{a[4], a[5], a[6], a[7]};
    if (blockIdx.x == 0 && threadIdx.x < 16) {
        int cc = threadIdx.x * 8;
        float b[8] = {};
        for (int k = 0; k < HD; ++k) {
            float w = b2m[k];
            const float* u = uW1b + k * HD + cc;
            float4 u0 = *(const float4*)u, u1 = *(const float4*)(u + 4);
            b[0] = fmaf(w, u0.x, b[0]); b[1] = fmaf(w, u0.y, b[1]);
            b[2] = fmaf(w, u0.z, b[2]); b[3] = fmaf(w, u0.w, b[3]);
            b[4] = fmaf(w, u1.x, b[4]); b[5] = fmaf(w, u1.y, b[5]);
            b[6] = fmaf(w, u1.z, b[6]); b[7] = fmaf(w, u1.w, b[7]);
        }
        *(float4*)(b2u + cc)     = float4{b[0], b[1], b[2], b[3]};
        *(float4*)(b2u + cc + 4) = float4{b[4], b[5], b[6], b[7]};
    }
}
__global__ __launch_bounds__(256) void wtL_k(const float* __restrict__ msgW1, const float* __restrict__ updW1,
                                             const float* __restrict__ updW2, const float* __restrict__ W2uF,
                                             unsigned short* __restrict__ dst) {
    int idx = blockIdx.x * 256 + threadIdx.x;   // 384 blocks = 98304 = 6*16384
    int m = idx >> 14;
    int r = idx & 16383;
    int n = r >> 7, k = r & 127;
    float v;
    switch (m) {
        case 0: v = msgW1[(long)k * HD + n]; break;
        case 1: v = msgW1[(long)(128 + k) * HD + n]; break;
        case 2: v = msgW1[(long)(256 + k) * HD + n]; break;
        case 3: v = updW1[(long)k * HD + n]; break;
        case 4: v = updW2[(long)k * HD + n]; break;
        default: v = W2uF[(long)k * HD + n]; break;
    }
    hl2 p = split2(v);
    dst[(long)m * 32768 + n * HD + k] = (unsigned short)p.hi;
    dst[(long)m * 32768 + 16384 + n * HD + k] = (unsigned short)p.lo;
}
__global__ __launch_bounds__(256) void wtE_k(const float* __restrict__ nW1, const float* __restrict__ nW2,
                                             const float* __restrict__ eW1, const float* __restrict__ eW2,
                                             unsigned short* __restrict__ dst) {
    int idx = blockIdx.x * 256 + threadIdx.x;   // 160 blocks = 40960
    float v; long off; int pos, sz;
    if (idx < 4096) {
        int n = idx >> 5, k = idx & 31;
        v = (k < 9) ? nW1[k * HD + n] : 0.f; off = 0; pos = idx; sz = 4096;
    } else if (idx < 20480) {
        int r = idx - 4096; int n = r >> 7, k = r & 127;
        v = nW2[k * HD + n]; off = 8192; pos = r; sz = 16384;
    } else if (idx < 24576) {
        int r = idx - 20480; int n = r >> 5, k = r & 31;
        v = (k < 10) ? eW1[k * HD + n] : 0.f; off = 40960; pos = r; sz = 4096;
    } else {
        int r = idx - 24576; int n = r >> 7, k = r & 127;
        v = eW2[k * HD + n]; off = 49152; pos = r; sz = 16384;
    }
    hl2 p = split2(v);
    dst[off + pos] = (unsigned short)p.hi;
    dst[off + sz + pos] = (unsigned short)p.lo;
}

// ---------------------------------------------------------------------------
// MFMA helpers. 256 threads = 4 waves. NEW ownership: wave w owns ALL 64 rows
// x col-tiles {2w, 2w+1}. B fragments preloaded ONCE per GEMM into registers
// (2 ct x 4 ks x hi/lo = 64 VGPR) -> main loop is pure ds_read + MFMA.
// ---------------------------------------------------------------------------
__device__ __forceinline__ void stageA_f32_split(short* __restrict__ At, short* __restrict__ Al,
                                                 const float* __restrict__ A, int bm, int M, int tid) {
#pragma unroll
    for (int t = 0; t < 4; ++t) {
        int c = tid + t * 256;
        int row = c >> 4, k8 = (c & 15) * 8;
        int gr = bm + row;
        s8 vh = (s8)0, vl = (s8)0;
        if (gr < M) {
            const float* p = A + (long)gr * HD + k8;
            f4 a = *(const f4*)p, b = *(const f4*)(p + 4);
#pragma unroll
            for (int i = 0; i < 4; ++i) {
                hl2 pa = split2(a[i]);
                hl2 pb = split2(b[i]);
                vh[i] = pa.hi; vl[i] = pa.lo;
                vh[4 + i] = pb.hi; vl[4 + i] = pb.lo;
            }
        }
        *(s8*)(At + row * SA + k8) = vh;
        *(s8*)(Al + row * SA + k8) = vl;
    }
}
__device__ __forceinline__ void stageA_b16(short* __restrict__ At, const unsigned short* __restrict__ A,
                                           int bm, int M, int tid) {
#pragma unroll
    for (int t = 0; t < 4; ++t) {
        int c = tid + t * 256;
        int row = c >> 4, k8 = (c & 15) * 8;
        int gr = bm + row;
        s8 v = (s8)0;
        if (gr < M) v = *(const s8*)(A + (long)gr * HD + k8);
        *(s8*)(At + row * SA + k8) = v;
    }
}
// CSR segment-sum stage: At/Al <- hi/lo of sum over Pe rows [rowp[gr],rowp[gr+1])
__device__ __forceinline__ void stage_segsum_split(short* __restrict__ At, short* __restrict__ Al,
                                                   const unsigned short* __restrict__ Pe,
                                                   const int* __restrict__ rowp,
                                                   int bm, int M, int tid) {
#pragma unroll
    for (int t = 0; t < 4; ++t) {
        int c = tid + t * 256;
        int row = c >> 4, k8 = (c & 15) * 8;
        int gr = bm + row;
        float sum[8] = {};
        if (gr < M) {
            int e0 = rowp[gr], e1 = rowp[gr + 1];
            for (int e = e0; e < e1; ++e) {
                us8 v = *(const us8*)(Pe + (long)e * HD + k8);
#pragma unroll
                for (int i = 0; i < 8; ++i) sum[i] += b2f(v[i]);
            }
        }
        s8 vh, vl;
#pragma unroll
        for (int i = 0; i < 8; ++i) {
            hl2 p = split2(sum[i]);
            vh[i] = p.hi; vl[i] = p.lo;
        }
        *(s8*)(At + row * SA + k8) = vh;
        *(s8*)(Al + row * SA + k8) = vl;
    }
}
// preload wave's B fragments (col-tiles 2w, 2w+1) into registers
__device__ __forceinline__ void loadB2(s8 b[2][4], const unsigned short* __restrict__ W,
                                       int sw, int nk, int w, int lane) {
    const int r16 = lane & 15, q8 = (lane >> 4) * 8;
#pragma unroll
    for (int ct = 0; ct < 2; ++ct)
#pragma unroll 4
        for (int ks = 0; ks < nk; ++ks)
            b[ct][ks] = *(const s8*)((const short*)W + (long)((2 * w + ct) * 16 + r16) * sw + ks * 32 + q8);
}
// 3-pass fp32-accurate: acc += Ah@Bh + Al@Bh + Ah@Bl  (A from LDS, B in regs)
__device__ __forceinline__ void mfma3_reg(f4 acc[4][2], const short* __restrict__ At,
                                          const short* __restrict__ Al, int sa,
                                          const s8 bh[2][4], const s8 bl[2][4], int nk, int lane) {
    const int r16 = lane & 15, q8 = (lane >> 4) * 8;
#pragma unroll 4
    for (int ks = 0; ks < nk; ++ks)
#pragma unroll
        for (int rt = 0; rt < 4; ++rt) {
            s8 ah = *(const s8*)(At + (rt * 16 + r16) * sa + ks * 32 + q8);
            s8 al = *(const s8*)(Al + (rt * 16 + r16) * sa + ks * 32 + q8);
#pragma unroll
            for (int ct = 0; ct < 2; ++ct) {
                acc[rt][ct] = __builtin_amdgcn_mfma_f32_16x16x32_bf16(ah, bh[ct][ks], acc[rt][ct], 0, 0, 0);
                acc[rt][ct] = __builtin_amdgcn_mfma_f32_16x16x32_bf16(al, bh[ct][ks], acc[rt][ct], 0, 0, 0);
                acc[rt][ct] = __builtin_amdgcn_mfma_f32_16x16x32_bf16(ah, bl[ct][ks], acc[rt][ct], 0, 0, 0);
            }
        }
}
// 2-pass (A exact bf16): acc += A@Bh + A@Bl
__device__ __forceinline__ void mfmaE_reg(f4 acc[4][2], const short* __restrict__ At, int sa,
                                          const s8 bh[2][4], const s8 bl[2][4], int nk, int lane) {
    const int r16 = lane & 15, q8 = (lane >> 4) * 8;
#pragma unroll 4
    for (int ks = 0; ks < nk; ++ks)
#pragma unroll
        for (int rt = 0; rt < 4; ++rt) {
            s8 a = *(const s8*)(At + (rt * 16 + r16) * sa + ks * 32 + q8);
#pragma unroll
            for (int ct = 0; ct < 2; ++ct) {
                acc[rt][ct] = __builtin_amdgcn_mfma_f32_16x16x32_bf16(a, bh[ct][ks], acc[rt][ct], 0, 0, 0);
                acc[rt][ct] = __builtin_amdgcn_mfma_f32_16x16x32_bf16(a, bl[ct][ks], acc[rt][ct], 0, 0, 0);
            }
        }
}
// dump cols [half*64, half*64+64) into Cd; wave-pair (w>>1 == half) writes its tiles
__device__ __forceinline__ void dumpC_half2(float* __restrict__ Cd, const f4 acc[4][2],
                                            int half, int w, int lane) {
    if ((w >> 1) != half) return;
    const int col0 = lane & 15, rq = (lane >> 4) * 4;
    const int bc = (w & 1) * 2;
#pragma unroll
    for (int rt = 0; rt < 4; ++rt)
#pragma unroll
        for (int ct = 0; ct < 2; ++ct)
#pragma unroll
            for (int r = 0; r < 4; ++r)
                Cd[(rt * 16 + rq + r) * SC2 + (bc + ct) * 16 + col0] = acc[rt][ct][r];
}
#define ACC_ZERO2(acc) { f4 z_ = {0.f, 0.f, 0.f, 0.f}; \
    for (int r_ = 0; r_ < 4; ++r_) for (int c_ = 0; c_ < 2; ++c_) acc[r_][c_] = z_; }

// ---------------------------------------------------------------------------
// dual GEMM: Hs = h@W1a, Hd = h@W1b (bf16 out), shared split-A stage
// ---------------------------------------------------------------------------
__global__ __launch_bounds__(256) void dual_k(const float* __restrict__ h,
                                              const unsigned short* __restrict__ W1aT,
                                              const unsigned short* __restrict__ W1bT,
                                              unsigned short* __restrict__ Hs, unsigned short* __restrict__ Hd,
                                              int M) {
    __shared__ __align__(16) short At[64 * SA];
    __shared__ __align__(16) short Al[64 * SA];
    __shared__ __align__(16) float Cd[64 * SC2];
    const int tid = threadIdx.x, lane = tid & 63, w = tid >> 6, tx = tid & 15, ty = tid >> 4;
    const int bm = blockIdx.x * 64;
    s8 bh[2][4], bl[2][4];
    loadB2(bh, W1aT, HD, 4, w, lane);
    loadB2(bl, W1aT + 16384, HD, 4, w, lane);
    stageA_f32_split(At, Al, h, bm, M, tid);
    __syncthreads();
    f4 acc[4][2]; ACC_ZERO2(acc);
    mfma3_reg(acc, At, Al, SA, bh, bl, 4, lane);
    loadB2(bh, W1bT, HD, 4, w, lane);
    loadB2(bl, W1bT + 16384, HD, 4, w, lane);
#pragma unroll
    for (int half = 0; half < 2; ++half) {
        __syncthreads();
        dumpC_half2(Cd, acc, half, w, lane);
        __syncthreads();
        int c4 = half * 64 + tx * 4;
#pragma unroll
        for (int i = 0; i < 4; ++i) {
            int row = ty * 4 + i, gr = bm + row;
            if (gr >= M) continue;
            f4 v = *(const f4*)(Cd + row * SC2 + tx * 4);
            us4 o;
#pragma unroll
            for (int j = 0; j < 4; ++j) o[j] = f2b(v[j]);
            *(us4*)(Hs + (long)gr * HD + c4) = o;
        }
    }
    ACC_ZERO2(acc);
    mfma3_reg(acc, At, Al, SA, bh, bl, 4, lane);
#pragma unroll
    for (int half = 0; half < 2; ++half) {
        __syncthreads();
        dumpC_half2(Cd, acc, half, w, lane);
        __syncthreads();
        int c4 = half * 64 + tx * 4;
#pragma unroll
        for (int i = 0; i < 4; ++i) {
            int row = ty * 4 + i, gr = bm + row;
            if (gr >= M) continue;
            f4 v = *(const f4*)(Cd + row * SC2 + tx * 4);
            us4 o;
#pragma unroll
            for (int j = 0; j < 4; ++j) o[j] = f2b(v[j]);
            *(us4*)(Hd + (long)gr * HD + c4) = o;
        }
    }
}

// ---------------------------------------------------------------------------
// edge: Pe[edge] = relu(eS@W1c + b1 + Hs[src] + Hd[dst])  (no atomics)
// ---------------------------------------------------------------------------
__global__ __launch_bounds__(256) void edge_k(const unsigned short* __restrict__ eS,
                                              const unsigned short* __restrict__ Hs,
                                              const unsigned short* __restrict__ Hd,
                                              const int* __restrict__ srcS, const int* __restrict__ dstS,
                                              const unsigned short* __restrict__ W1cT,
                                              const float* __restrict__ b1,
                                              unsigned short* __restrict__ Pe) {
    __shared__ __align__(16) short At[64 * SA];
    __shared__ __align__(16) float Cd[64 * SC2];
    const int tid = threadIdx.x, lane = tid & 63, w = tid >> 6, tx = tid & 15, ty = tid >> 4;
    const int bm = blockIdx.x * 64;
    s8 bh[2][4], bl[2][4];
    loadB2(bh, W1cT, HD, 4, w, lane);
    loadB2(bl, W1cT + 16384, HD, 4, w, lane);
    stageA_b16(At, eS, bm, NE, tid);
    __syncthreads();
    f4 acc[4][2]; ACC_ZERO2(acc);
    mfmaE_reg(acc, At, SA, bh, bl, 4, lane);
#pragma unroll
    for (int half = 0; half < 2; ++half) {
        __syncthreads();
        dumpC_half2(Cd, acc, half, w, lane);
        __syncthreads();
        int c4 = half * 64 + tx * 4;
        f4 bv = *(const f4*)(b1 + c4);
#pragma unroll
        for (int i = 0; i < 4; ++i) {
            int row = ty * 4 + i, edge = bm + row;
            int s = srcS[edge], d = dstS[edge];
            us4 hs = *(const us4*)(Hs + (long)s * HD + c4);
            us4 hd = *(const us4*)(Hd + (long)d * HD + c4);
            f4 cv = *(const f4*)(Cd + row * SC2 + tx * 4);
            us4 o;
#pragma unroll
            for (int j = 0; j < 4; ++j)
                o[j] = f2b(fmaxf(cv[j] + bv[j] + b2f(hs[j]) + b2f(hd[j]), 0.f));
            *(us4*)(Pe + (long)edge * HD + c4) = o;
        }
    }
}

// ---------------------------------------------------------------------------
// update: S = segsum(Pe); T = relu(h@uW1a + S@W2u + deg*b2u + ub1); h += T@uW2 + ub2
// ---------------------------------------------------------------------------
__global__ __launch_bounds__(256) void upd_k(float* __restrict__ h,
                                             const unsigned short* __restrict__ Pe,
                                             const int* __restrict__ rowp,
                                             const unsigned short* __restrict__ uW1aT,
                                             const unsigned short* __restrict__ W2uT,
                                             const float* __restrict__ ub1, const float* __restrict__ b2u,
                                             const float* __restrict__ deg,
                                             const unsigned short* __restrict__ uW2T,
                                             const float* __restrict__ ub2, int M) {
    __shared__ __align__(16) short At[64 * SA];
    __shared__ __align__(16) short Al[64 * SA];
    __shared__ __align__(16) float Cd[64 * SC2];
    const int tid = threadIdx.x, lane = tid & 63, w = tid >> 6, tx = tid & 15, ty = tid >> 4;
    const int bm = blockIdx.x * 64;
    s8 bh[2][4], bl[2][4];
    f4 acc[4][2]; ACC_ZERO2(acc);
    loadB2(bh, uW1aT, HD, 4, w, lane);
    loadB2(bl, uW1aT + 16384, HD, 4, w, lane);
    stageA_f32_split(At, Al, h, bm, M, tid);
    __syncthreads();
    mfma3_reg(acc, At, Al, SA, bh, bl, 4, lane);
    loadB2(bh, W2uT, HD, 4, w, lane);
    loadB2(bl, W2uT + 16384, HD, 4, w, lane);
    __syncthreads();
    stage_segsum_split(At, Al, Pe, rowp, bm, M, tid);
    __syncthreads();
    mfma3_reg(acc, At, Al, SA, bh, bl, 4, lane);
    loadB2(bh, uW2T, HD, 4, w, lane);
    loadB2(bl, uW2T + 16384, HD, 4, w, lane);
    __syncthreads();
    // T = relu(acc + ub1 + deg*b2u) -> At/Al (hi/lo); wave w owns cols 2w,2w+1
    {
        const int col0 = lane & 15, rq = (lane >> 4) * 4;
        float u1[2], u2[2];
#pragma unroll
        for (int ct = 0; ct < 2; ++ct) {
            int col = (2 * w + ct) * 16 + col0;
            u1[ct] = ub1[col]; u2[ct] = b2u[col];
        }
        float dgv[16];
#pragma unroll
        for (int rt = 0; rt < 4; ++rt)
#pragma unroll
            for (int r = 0; r < 4; ++r) {
                int gr = bm + rt * 16 + rq + r;
                dgv[rt * 4 + r] = (gr < M) ? deg[gr] : 0.f;
            }
#pragma unroll
        for (int rt = 0; rt < 4; ++rt)
#pragma unroll
            for (int ct = 0; ct < 2; ++ct)
#pragma unroll
                for (int r = 0; r < 4; ++r) {
                    float p = fmaxf(acc[rt][ct][r] + u1[ct] + dgv[rt * 4 + r] * u2[ct], 0.f);
                    hl2 pp = split2(p);
                    int off = (rt * 16 + rq + r) * SA + (2 * w + ct) * 16 + col0;
                    At[off] = pp.hi;
                    Al[off] = pp.lo;
                }
    }
    __syncthreads();
    ACC_ZERO2(acc);
    mfma3_reg(acc, At, Al, SA, bh, bl, 4, lane);
#pragma unroll
    for (int half = 0; half < 2; ++half) {
        __syncthreads();
        dumpC_half2(Cd, acc, half, w, lane);
        __syncthreads();
        int c4 = half * 64 + tx * 4;
        f4 u0 = *(const f4*)(ub2 + c4);
#pragma unroll
        for (int i = 0; i < 4; ++i) {
            int row = ty * 4 + i, gr = bm + row;
            if (gr >= M) continue;
            float* hp = h + (long)gr * HD + c4;
            f4 a = *(f4*)hp;
            f4 cv = *(const f4*)(Cd + row * SC2 + tx * 4);
#pragma unroll
            for (int j = 0; j < 4; ++j) a[j] += cv[j] + u0[j];
            *(f4*)hp = a;
        }
    }
}

// ---------------------------------------------------------------------------
// fused 2-layer encoder (split-precision MFMA). SCAT: bf16 scatter via pos.
// ---------------------------------------------------------------------------
template<bool SCAT>
__global__ __launch_bounds__(256) void enc_k(const float* __restrict__ A, int KIN,
                                             const unsigned short* __restrict__ W1T, const float* __restrict__ b1,
                                             const unsigned short* __restrict__ W2T, const float* __restrict__ b2,
                                             float* __restrict__ outF, unsigned short* __restrict__ outB,
                                             const int* __restrict__ pos, int M) {
    __shared__ __align__(16) short At[64 * SA];
    __shared__ __align__(16) short Al[64 * SA];
    __shared__ __align__(16) float Cd[64 * SC2];
    const int tid = threadIdx.x, lane = tid & 63, w = tid >> 6, tx = tid & 15, ty = tid >> 4;
    const int bm = blockIdx.x * 64;
    s8 bh[2][4], bl[2][4];
    loadB2(bh, W1T, 32, 1, w, lane);
    loadB2(bl, W1T + 4096, 32, 1, w, lane);
    {
        int row = tid >> 2, k8 = (tid & 3) * 8;
        int gr = bm + row;
        s8 vh = (s8)0, vl = (s8)0;
        if (gr < M) {
#pragma unroll
            for (int i = 0; i < 8; ++i) {
                int k = k8 + i;
                if (k < KIN) {
                    hl2 p = split2(A[(long)gr * KIN + k]);
                    vh[i] = p.hi; vl[i] = p.lo;
                }
            }
        }
        *(s8*)(At + row * SA32 + k8) = vh;
        *(s8*)(Al + row * SA32 + k8) = vl;
    }
    __syncthreads();
    f4 acc[4][2]; ACC_ZERO2(acc);
    mfma3_reg(acc, At, Al, SA32, bh, bl, 1, lane);
    loadB2(bh, W2T, HD, 4, w, lane);
    loadB2(bl, W2T + 16384, HD, 4, w, lane);
    __syncthreads();
    // P = relu(acc + b1) -> At/Al (K=128 layout); wave w owns cols 2w,2w+1
    {
        const int col0 = lane & 15, rq = (lane >> 4) * 4;
        float bb[2];
#pragma unroll
        for (int ct = 0; ct < 2; ++ct) bb[ct] = b1[(2 * w + ct) * 16 + col0];
#pragma unroll
        for (int rt = 0; rt < 4; ++rt)
#pragma unroll
            for (int ct = 0; ct < 2; ++ct)
#pragma unroll
                for (int r = 0; r < 4; ++r) {
                    float p = fmaxf(acc[rt][ct][r] + bb[ct], 0.f);
                    hl2 pp = split2(p);
                    int off = (rt * 16 + rq + r) * SA + (2 * w + ct) * 16 + col0;
                    At[off] = pp.hi;
                    Al[off] = pp.lo;
                }
    }
    __syncthreads();
    ACC_ZERO2(acc);
    mfma3_reg(acc, At, Al, SA, bh, bl, 4, lane);
#pragma unroll
    for (int half = 0; half < 2; ++half) {
        __syncthreads();
        dumpC_half2(Cd, acc, half, w, lane);
        __syncthreads();
        int c4 = half * 64 + tx * 4;
        f4 bv = *(const f4*)(b2 + c4);
#pragma unroll
        for (int i = 0; i < 4; ++i) {
            int row = ty * 4 + i, gr = bm + row;
            if (gr >= M) continue;
            f4 cv = *(const f4*)(Cd + row * SC2 + tx * 4);
            if constexpr (SCAT) {
                int p = pos[gr];
                us4 o;
#pragma unroll
                for (int j = 0; j < 4; ++j) o[j] = f2b(cv[j] + bv[j]);
                *(us4*)(outB + (long)p * HD + c4) = o;
            } else {
                f4 o;
#pragma unroll
                for (int j = 0; j < 4; ++j) o[j] = cv[j] + bv[j];
                *(f4*)(outF + (long)gr * HD + c4) = o;
            }
        }
    }
}

// ---------------------------------------------------------------------------
// fused decoder (VALU, known-correct fp32)
// ---------------------------------------------------------------------------
__global__ __launch_bounds__(256) void dec_k(
    const float* __restrict__ h,
    const float* __restrict__ W1, const float* __restrict__ b1,
    const float* __restrict__ W2, const float* __restrict__ b2,
    const float* __restrict__ W3, const float* __restrict__ b3,
    const float* __restrict__ bc_disp, const float* __restrict__ bc_rot,
    float* __restrict__ outp, int M)
{
    __shared__ float As[64][33];
    __shared__ float Ws[32][HD];
    __shared__ float P[64][HD + 1];
    __shared__ float D2[64][65];
    const int tid = threadIdx.x, tx = tid & 15, ty = tid >> 4;
    const int bm = blockIdx.x * 64;
    float acc[4][8] = {};

    for (int kk = 0; kk < HD; kk += 32) {
        int r = tid >> 2, cc0 = (tid & 3) * 8, gr = bm + r;
#pragma unroll
        for (int i = 0; i < 8; ++i)
            As[r][cc0 + i] = (gr < M) ? h[(long)gr * HD + kk + cc0 + i] : 0.f;
        int k = tid >> 3, n0 = (tid & 7) * 16;
#pragma unroll
        for (int i = 0; i < 16; ++i)
            Ws[k][n0 + i] = W1[(kk + k) * HD + n0 + i];
        __syncthreads();
#pragma unroll
        for (int k2 = 0; k2 < 32; ++k2) {
            float a0 = As[ty * 4 + 0][k2], a1 = As[ty * 4 + 1][k2];
            float a2 = As[ty * 4 + 2][k2], a3 = As[ty * 4 + 3][k2];
#pragma unroll
            for (int j = 0; j < 8; ++j) {
                float ww = Ws[k2][tx * 8 + j];
                acc[0][j] = fmaf(a0, ww, acc[0][j]);
                acc[1][j] = fmaf(a1, ww, acc[1][j]);
                acc[2][j] = fmaf(a2, ww, acc[2][j]);
                acc[3][j] = fmaf(a3, ww, acc[3][j]);
            }
        }
        __syncthreads();
    }
#pragma unroll
    for (int i = 0; i < 4; ++i) {
        int row = ty * 4 + i;
#pragma unroll
        for (int j = 0; j < 8; ++j) {
            int col = tx * 8 + j;
            P[row][col] = fmaxf(acc[i][j] + b1[col], 0.f);
        }
    }
    __syncthreads();
    float acc2[4][4] = {};
    for (int kk = 0; kk < HD; kk += 32) {
        int idx = tid * 8;
        int k = idx >> 6, n0 = idx & 63;
#pragma unroll
        for (int i = 0; i < 8; ++i)
            Ws[k][n0 + i] = W2[(kk + k) * 64 + n0 + i];
        __syncthreads();
#pragma unroll
        for (int k2 = 0; k2 < 32; ++k2) {
            float a0 = P[ty * 4 + 0][kk + k2], a1 = P[ty * 4 + 1][kk + k2];
            float a2 = P[ty * 4 + 2][kk + k2], a3 = P[ty * 4 + 3][kk + k2];
#pragma unroll
            for (int j = 0; j < 4; ++j) {
                float ww = Ws[k2][tx * 4 + j];
                acc2[0][j] = fmaf(a0, ww, acc2[0][j]);
                acc2[1][j] = fmaf(a1, ww, acc2[1][j]);
                acc2[2][j] = fmaf(a2, ww, acc2[2][j]);
                acc2[3][j] = fmaf(a3, ww, acc2[3][j]);
            }
        }
        __syncthreads();
    }
#pragma unroll
    for (int i = 0; i < 4; ++i) {
        int row = ty * 4 + i;
#pragma unroll
        for (int j = 0; j < 4; ++j) {
            int col = tx * 4 + j;
            D2[row][col] = fmaxf(acc2[i][j] + b2[col], 0.f);
        }
    }
    __syncthreads();
    if (tid < 64) {
        int gr = bm + tid;
        if (gr < M) {
            float a0 = b3[0], a1 = b3[1], a2 = b3[2];
#pragma unroll
            for (int k = 0; k < 64; ++k) {
                float v = D2[tid][k];
                a0 = fmaf(v, W3[k * 3 + 0], a0);
                a1 = fmaf(v, W3[k * 3 + 1], a1);
                a2 = fmaf(v, W3[k * 3 + 2], a2);
            }
            outp[gr * 3 + 0] = a0 * (1.f - bc_disp[gr * 2 + 0]);
            outp[gr * 3 + 1] = a1 * (1.f - bc_disp[gr * 2 + 1]);
            outp[gr * 3 + 2] = a2 * (1.f - bc_rot[gr]);
        }
    }
}

// ---------------------------------------------------------------------------
extern "C" void kernel_launch(void* const* d_in, const int* in_sizes, int n_in,
                              void* d_out, int out_size, void* d_ws, size_t ws_size,
                              hipStream_t stream)
{
    const float* x        = (const float*)d_in[0];
    const float* eattr    = (const float*)d_in[1];
    const int*   eidx     = (const int*)d_in[2];
    const float* bc_disp  = (const float*)d_in[3];
    const float* bc_rot   = (const float*)d_in[4];
    const float* enc_n_W1 = (const float*)d_in[5];
    const float* enc_n_b1 = (const float*)d_in[6];
    const float* enc_n_W2 = (const float*)d_in[7];
    const float* enc_n_b2 = (const float*)d_in[8];
    const float* enc_e_W1 = (const float*)d_in[9];
    const float* enc_e_b1 = (const float*)d_in[10];
    const float* enc_e_W2 = (const float*)d_in[11];
    const float* enc_e_b2 = (const float*)d_in[12];
    const float* msg_W1   = (const float*)d_in[13];
    const float* msg_b1   = (const float*)d_in[14];
    const float* msg_W2   = (const float*)d_in[15];
    const float* msg_b2   = (const float*)d_in[16];
    const float* upd_W1   = (const float*)d_in[17];
    const float* upd_b1   = (const float*)d_in[18];
    const float* upd_W2   = (const float*)d_in[19];
    const float* upd_b2   = (const float*)d_in[20];
    const float* dec_W1   = (const float*)d_in[21];
    const float* dec_b1   = (const float*)d_in[22];
    const float* dec_W2   = (const float*)d_in[23];
    const float* dec_b2   = (const float*)d_in[24];
    const float* dec_W3   = (const float*)d_in[25];
    const float* dec_b3   = (const float*)d_in[26];

    const int* src = eidx;
    const int* dst = eidx + NE;

    // workspace layout
    char* base = (char*)d_ws;
    float* h  = (float*)base;                                   // NN*HD f32
    unsigned short* Hs = (unsigned short*)(h + (long)NN * HD);  // NN*HD bf16
    unsigned short* Hd = Hs + (long)NN * HD;                    // NN*HD bf16
    unsigned short* eS = Hd + (long)NN * HD;                    // NE*HD bf16
    unsigned short* Pe = eS + (long)NE * HD;                    // NE*HD bf16
    float* W2uF = (float*)(Pe + (long)NE * HD);                 // 6*128*128 f32
    float* b2uA = W2uF + 6 * HD * HD;                           // 6*128 f32
    unsigned short* WtL = (unsigned short*)(b2uA + 6 * HD);     // 6*6*32768 bf16
    unsigned short* WtE = WtL + 6L * 6 * 32768;                 // 81920 bf16
    float* deg = (float*)(WtE + 81920);                         // NN f32
    int* rowp  = (int*)(deg + NN);                              // NN+1
    int* cnt   = rowp + (NN + 1);                               // NN
    int* posb  = cnt + NN;                                      // NE
    int* srcS  = posb + NE;                                     // NE
    int* dstS  = srcS + NE;                                     // NE
    int* bsum  = dstS + NE;                                     // 256
    size_t need = (size_t)((char*)(bsum + 256) - base);
    if (ws_size < need) {
        zerof_k<<<(unsigned)((out_size + 255) / 256), 256, 0, stream>>>((float*)d_out, out_size);
        return;
    }

    dim3 blk(256);
    const unsigned gN  = (NN + 63) / 64;    // 782
    const unsigned gE  = NE / 64;           // 3125
    const unsigned gNc = (NN + 255) / 256;  // 196
    const unsigned gEc = (NE + 255) / 256;  // 782

    // --- prologue: counting sort of edges by dst ---
    zeroi_k<<<gNc, blk, 0, stream>>>(cnt, NN);
    hist_k<<<gEc, blk, 0, stream>>>(dst, cnt);
    scan1_k<<<gNc, blk, 0, stream>>>(cnt, bsum);
    scan2_k<<<1, blk, 0, stream>>>(bsum, (int)gNc);
    scan3_k<<<gNc, blk, 0, stream>>>(cnt, bsum, rowp, deg);
    zeroi_k<<<gNc, blk, 0, stream>>>(cnt, NN);
    posbuild_k<<<gEc, blk, 0, stream>>>(src, dst, rowp, cnt, posb, srcS, dstS);

    // --- weight prep ---
    for (int l = 0; l < 6; ++l) {
        mini_k<<<8, blk, 0, stream>>>(msg_W2 + (long)l * HD * HD,
                                      upd_W1 + (long)l * 256 * HD + 128 * HD,
                                      msg_b2 + (long)l * HD,
                                      W2uF + (long)l * HD * HD, b2uA + (long)l * HD);
    }
    for (int l = 0; l < 6; ++l) {
        wtL_k<<<384, blk, 0, stream>>>(msg_W1 + (long)l * 384 * HD,
                                       upd_W1 + (long)l * 256 * HD,
                                       upd_W2 + (long)l * HD * HD,
                                       W2uF + (long)l * HD * HD,
                                       WtL + (long)l * 6 * 32768);
    }
    wtE_k<<<160, blk, 0, stream>>>(enc_n_W1, enc_n_W2, enc_e_W1, enc_e_W2, WtE);

    // --- encoders ---
    enc_k<false><<<gN, blk, 0, stream>>>(x, 9, WtE, enc_n_b1, WtE + 8192, enc_n_b2,
                                         h, nullptr, nullptr, NN);
    enc_k<true><<<gE, blk, 0, stream>>>(eattr, 10, WtE + 40960, enc_e_b1, WtE + 49152, enc_e_b2,
                                        nullptr, eS, posb, NE);

    // --- message-passing layers ---
    for (int l = 0; l < 6; ++l) {
        const unsigned short* Wt = WtL + (long)l * 6 * 32768;
        const float* b1  = msg_b1 + (long)l * HD;
        const float* ub1 = upd_b1 + (long)l * HD;
        const float* ub2 = upd_b2 + (long)l * HD;
        const float* b2u = b2uA + (long)l * HD;

        dual_k<<<gN, blk, 0, stream>>>(h, Wt + 0L * 32768, Wt + 1L * 32768, Hs, Hd, NN);
        edge_k<<<gE, blk, 0, stream>>>(eS, Hs, Hd, srcS, dstS, Wt + 2L * 32768, b1, Pe);
        upd_k<<<gN, blk, 0, stream>>>(h, Pe, rowp, Wt + 3L * 32768, Wt + 5L * 32768,
                                      ub1, b2u, deg, Wt + 4L * 32768, ub2, NN);
    }

    // --- decoder ---
    dec_k<<<gN, blk, 0, stream>>>(h, dec_W1, dec_b1, dec_W2, dec_b2, dec_W3, dec_b3,
                                  bc_disp, bc_rot, (float*)d_out, NN);
}

// Round 9
// 1024.779 us; speedup vs baseline: 2.8192x; 1.0990x over previous
//
#include <hip/hip_runtime.h>

#define NN 50000
#define NE 200000
#define HD 128

typedef unsigned short us4 __attribute__((ext_vector_type(4)));
typedef unsigned short us8 __attribute__((ext_vector_type(8)));
typedef short s8 __attribute__((ext_vector_type(8)));
typedef float f4 __attribute__((ext_vector_type(4)));

#define SA 136    // bf16 LDS k-stride for K=128 (+8 pad) -> 272B rows
#define SA32 40   // bf16 LDS k-stride for K=32 (+8 pad)
#define SC2 68    // fp32 LDS dump col-stride for 64-col half (+4 pad)

__device__ __forceinline__ float b2f(unsigned short u) {
    union { unsigned i; float f; } v; v.i = ((unsigned)u) << 16; return v.f;
}
__device__ __forceinline__ unsigned short f2b(float x) {
    union { float f; unsigned i; } v; v.f = x;
    unsigned r = v.i + 0x7fffu + ((v.i >> 16) & 1u);
    return (unsigned short)(r >> 16);
}
struct hl2 { short hi, lo; };
__device__ __forceinline__ hl2 split2(float x) {
    unsigned short h = f2b(x);
    hl2 r;
    r.hi = (short)h;
    r.lo = (short)f2b(x - b2f(h));
    return r;
}

// ---------------------------------------------------------------------------
// zero / utility
// ---------------------------------------------------------------------------
__global__ __launch_bounds__(256) void zeroi_k(int* __restrict__ p, int n) {
    int i = blockIdx.x * 256 + threadIdx.x;
    if (i < n) p[i] = 0;
}
__global__ __launch_bounds__(256) void zerof_k(float* __restrict__ p, long n) {
    long i = (long)blockIdx.x * 256 + threadIdx.x;
    if (i < n) p[i] = 0.f;
}

// ---------------------------------------------------------------------------
// counting-sort prologue (proven)
// ---------------------------------------------------------------------------
__global__ __launch_bounds__(256) void hist_k(const int* __restrict__ dst, int* __restrict__ cnt) {
    int i = blockIdx.x * 256 + threadIdx.x;
    if (i < NE) atomicAdd(&cnt[dst[i]], 1);
}
__global__ __launch_bounds__(256) void scan1_k(const int* __restrict__ cnt, int* __restrict__ bsum) {
    __shared__ int sc[256];
    int i = blockIdx.x * 256 + threadIdx.x;
    sc[threadIdx.x] = (i < NN) ? cnt[i] : 0;
    __syncthreads();
    for (int off = 128; off > 0; off >>= 1) {
        if (threadIdx.x < off) sc[threadIdx.x] += sc[threadIdx.x + off];
        __syncthreads();
    }
    if (threadIdx.x == 0) bsum[blockIdx.x] = sc[0];
}
__global__ __launch_bounds__(256) void scan2_k(int* __restrict__ bsum, int nb) {
    __shared__ int sc[256];
    int t = threadIdx.x;
    int v = (t < nb) ? bsum[t] : 0;
    sc[t] = v;
    __syncthreads();
    for (int off = 1; off < 256; off <<= 1) {
        int a = (t >= off) ? sc[t - off] : 0;
        __syncthreads();
        sc[t] += a;
        __syncthreads();
    }
    if (t < nb) bsum[t] = sc[t] - v;
}
__global__ __launch_bounds__(256) void scan3_k(const int* __restrict__ cnt, const int* __restrict__ bsum,
                                               int* __restrict__ rp, float* __restrict__ deg) {
    __shared__ int sc[256];
    int t = threadIdx.x;
    int i = blockIdx.x * 256 + t;
    int v = (i < NN) ? cnt[i] : 0;
    sc[t] = v;
    __syncthreads();
    for (int off = 1; off < 256; off <<= 1) {
        int a = (t >= off) ? sc[t - off] : 0;
        __syncthreads();
        sc[t] += a;
        __syncthreads();
    }
    int incl = sc[t];
    if (i < NN) {
        rp[i] = bsum[blockIdx.x] + incl - v;
        deg[i] = (float)v;
        if (i == NN - 1) rp[NN] = bsum[blockIdx.x] + incl;
    }
}
__global__ __launch_bounds__(256) void posbuild_k(const int* __restrict__ src, const int* __restrict__ dst,
                                                  const int* __restrict__ rp, int* __restrict__ cur,
                                                  int* __restrict__ pos, int* __restrict__ srcS,
                                                  int* __restrict__ dstS) {
    int i = blockIdx.x * 256 + threadIdx.x;
    if (i >= NE) return;
    int d = dst[i];
    int p = rp[d] + atomicAdd(&cur[d], 1);
    pos[i] = p;
    srcS[p] = src[i];
    dstS[p] = d;
}

// ---------------------------------------------------------------------------
// weight prep
// ---------------------------------------------------------------------------
__global__ __launch_bounds__(256) void mini_k(const float* __restrict__ W2m, const float* __restrict__ uW1b,
                                              const float* __restrict__ b2m,
                                              float* __restrict__ W2u, float* __restrict__ b2u) {
    int r = blockIdx.x * 16 + (threadIdx.x >> 4);
    int c0 = (threadIdx.x & 15) * 8;
    float a[8] = {};
    for (int k = 0; k < HD; ++k) {
        float w = W2m[r * HD + k];
        const float* u = uW1b + k * HD + c0;
        float4 u0 = *(const float4*)u, u1 = *(const float4*)(u + 4);
        a[0] = fmaf(w, u0.x, a[0]); a[1] = fmaf(w, u0.y, a[1]);
        a[2] = fmaf(w, u0.z, a[2]); a[3] = fmaf(w, u0.w, a[3]);
        a[4] = fmaf(w, u1.x, a[4]); a[5] = fmaf(w, u1.y, a[5]);
        a[6] = fmaf(w, u1.z, a[6]); a[7] = fmaf(w, u1.w, a[7]);
    }
    *(float4*)(W2u + r * HD + c0)     = float4{a[0], a[1], a[2], a[3]};
    *(float4*)(W2u + r * HD + c0 + 4) = float4{a[4], a[5], a[6], a[7]};
    if (blockIdx.x == 0 && threadIdx.x < 16) {
        int cc = threadIdx.x * 8;
        float b[8] = {};
        for (int k = 0; k < HD; ++k) {
            float w = b2m[k];
            const float* u = uW1b + k * HD + cc;
            float4 u0 = *(const float4*)u, u1 = *(const float4*)(u + 4);
            b[0] = fmaf(w, u0.x, b[0]); b[1] = fmaf(w, u0.y, b[1]);
            b[2] = fmaf(w, u0.z, b[2]); b[3] = fmaf(w, u0.w, b[3]);
            b[4] = fmaf(w, u1.x, b[4]); b[5] = fmaf(w, u1.y, b[5]);
            b[6] = fmaf(w, u1.z, b[6]); b[7] = fmaf(w, u1.w, b[7]);
        }
        *(float4*)(b2u + cc)     = float4{b[0], b[1], b[2], b[3]};
        *(float4*)(b2u + cc + 4) = float4{b[4], b[5], b[6], b[7]};
    }
}
__global__ __launch_bounds__(256) void wtL_k(const float* __restrict__ msgW1, const float* __restrict__ updW1,
                                             const float* __restrict__ updW2, const float* __restrict__ W2uF,
                                             unsigned short* __restrict__ dst) {
    int idx = blockIdx.x * 256 + threadIdx.x;   // 384 blocks = 98304 = 6*16384
    int m = idx >> 14;
    int r = idx & 16383;
    int n = r >> 7, k = r & 127;
    float v;
    switch (m) {
        case 0: v = msgW1[(long)k * HD + n]; break;
        case 1: v = msgW1[(long)(128 + k) * HD + n]; break;
        case 2: v = msgW1[(long)(256 + k) * HD + n]; break;
        case 3: v = updW1[(long)k * HD + n]; break;
        case 4: v = updW2[(long)k * HD + n]; break;
        default: v = W2uF[(long)k * HD + n]; break;
    }
    hl2 p = split2(v);
    dst[(long)m * 32768 + n * HD + k] = (unsigned short)p.hi;
    dst[(long)m * 32768 + 16384 + n * HD + k] = (unsigned short)p.lo;
}
__global__ __launch_bounds__(256) void wtE_k(const float* __restrict__ nW1, const float* __restrict__ nW2,
                                             const float* __restrict__ eW1, const float* __restrict__ eW2,
                                             unsigned short* __restrict__ dst) {
    int idx = blockIdx.x * 256 + threadIdx.x;   // 160 blocks = 40960
    float v; long off; int pos, sz;
    if (idx < 4096) {
        int n = idx >> 5, k = idx & 31;
        v = (k < 9) ? nW1[k * HD + n] : 0.f; off = 0; pos = idx; sz = 4096;
    } else if (idx < 20480) {
        int r = idx - 4096; int n = r >> 7, k = r & 127;
        v = nW2[k * HD + n]; off = 8192; pos = r; sz = 16384;
    } else if (idx < 24576) {
        int r = idx - 20480; int n = r >> 5, k = r & 31;
        v = (k < 10) ? eW1[k * HD + n] : 0.f; off = 40960; pos = r; sz = 4096;
    } else {
        int r = idx - 24576; int n = r >> 7, k = r & 127;
        v = eW2[k * HD + n]; off = 49152; pos = r; sz = 16384;
    }
    hl2 p = split2(v);
    dst[off + pos] = (unsigned short)p.hi;
    dst[off + sz + pos] = (unsigned short)p.lo;
}
// decoder weights: dW1 [128,128] -> [n][k] hi(0)/lo(16384); dW2 [128,64] -> [64n][128k] hi(32768)/lo(40960)
__global__ __launch_bounds__(256) void wtD_k(const float* __restrict__ dW1, const float* __restrict__ dW2,
                                             unsigned short* __restrict__ dst) {
    int idx = blockIdx.x * 256 + threadIdx.x;   // 96 blocks = 24576
    if (idx < 16384) {
        int n = idx >> 7, k = idx & 127;
        hl2 p = split2(dW1[k * HD + n]);
        dst[idx] = (unsigned short)p.hi;
        dst[16384 + idx] = (unsigned short)p.lo;
    } else {
        int r = idx - 16384;   // 8192
        int n = r >> 7, k = r & 127;
        hl2 p = split2(dW2[k * 64 + n]);
        dst[32768 + r] = (unsigned short)p.hi;
        dst[40960 + r] = (unsigned short)p.lo;
    }
}

// ---------------------------------------------------------------------------
// MFMA helpers. 256 threads = 4 waves; wave w owns ALL 64 rows x col-tiles
// {2w, 2w+1}. B fragments preloaded ONCE per GEMM into registers.
// ---------------------------------------------------------------------------
__device__ __forceinline__ void stageA_f32_split(short* __restrict__ At, short* __restrict__ Al,
                                                 const float* __restrict__ A, int bm, int M, int tid) {
#pragma unroll
    for (int t = 0; t < 4; ++t) {
        int c = tid + t * 256;
        int row = c >> 4, k8 = (c & 15) * 8;
        int gr = bm + row;
        s8 vh = (s8)0, vl = (s8)0;
        if (gr < M) {
            const float* p = A + (long)gr * HD + k8;
            f4 a = *(const f4*)p, b = *(const f4*)(p + 4);
#pragma unroll
            for (int i = 0; i < 4; ++i) {
                hl2 pa = split2(a[i]);
                hl2 pb = split2(b[i]);
                vh[i] = pa.hi; vl[i] = pa.lo;
                vh[4 + i] = pb.hi; vl[4 + i] = pb.lo;
            }
        }
        *(s8*)(At + row * SA + k8) = vh;
        *(s8*)(Al + row * SA + k8) = vl;
    }
}
__device__ __forceinline__ void stageA_b16(short* __restrict__ At, const unsigned short* __restrict__ A,
                                           int bm, int M, int tid) {
#pragma unroll
    for (int t = 0; t < 4; ++t) {
        int c = tid + t * 256;
        int row = c >> 4, k8 = (c & 15) * 8;
        int gr = bm + row;
        s8 v = (s8)0;
        if (gr < M) v = *(const s8*)(A + (long)gr * HD + k8);
        *(s8*)(At + row * SA + k8) = v;
    }
}
__device__ __forceinline__ void stage_segsum_split(short* __restrict__ At, short* __restrict__ Al,
                                                   const unsigned short* __restrict__ Pe,
                                                   const int* __restrict__ rowp,
                                                   int bm, int M, int tid) {
#pragma unroll
    for (int t = 0; t < 4; ++t) {
        int c = tid + t * 256;
        int row = c >> 4, k8 = (c & 15) * 8;
        int gr = bm + row;
        float sum[8] = {};
        if (gr < M) {
            int e0 = rowp[gr], e1 = rowp[gr + 1];
            for (int e = e0; e < e1; ++e) {
                us8 v = *(const us8*)(Pe + (long)e * HD + k8);
#pragma unroll
                for (int i = 0; i < 8; ++i) sum[i] += b2f(v[i]);
            }
        }
        s8 vh, vl;
#pragma unroll
        for (int i = 0; i < 8; ++i) {
            hl2 p = split2(sum[i]);
            vh[i] = p.hi; vl[i] = p.lo;
        }
        *(s8*)(At + row * SA + k8) = vh;
        *(s8*)(Al + row * SA + k8) = vl;
    }
}
__device__ __forceinline__ void loadB2(s8 b[2][4], const unsigned short* __restrict__ W,
                                       int sw, int nk, int w, int lane) {
    const int r16 = lane & 15, q8 = (lane >> 4) * 8;
#pragma unroll
    for (int ct = 0; ct < 2; ++ct)
#pragma unroll 4
        for (int ks = 0; ks < nk; ++ks)
            b[ct][ks] = *(const s8*)((const short*)W + (long)((2 * w + ct) * 16 + r16) * sw + ks * 32 + q8);
}
__device__ __forceinline__ void mfma3_reg(f4 acc[4][2], const short* __restrict__ At,
                                          const short* __restrict__ Al, int sa,
                                          const s8 bh[2][4], const s8 bl[2][4], int nk, int lane) {
    const int r16 = lane & 15, q8 = (lane >> 4) * 8;
#pragma unroll 4
    for (int ks = 0; ks < nk; ++ks)
#pragma unroll
        for (int rt = 0; rt < 4; ++rt) {
            s8 ah = *(const s8*)(At + (rt * 16 + r16) * sa + ks * 32 + q8);
            s8 al = *(const s8*)(Al + (rt * 16 + r16) * sa + ks * 32 + q8);
#pragma unroll
            for (int ct = 0; ct < 2; ++ct) {
                acc[rt][ct] = __builtin_amdgcn_mfma_f32_16x16x32_bf16(ah, bh[ct][ks], acc[rt][ct], 0, 0, 0);
                acc[rt][ct] = __builtin_amdgcn_mfma_f32_16x16x32_bf16(al, bh[ct][ks], acc[rt][ct], 0, 0, 0);
                acc[rt][ct] = __builtin_amdgcn_mfma_f32_16x16x32_bf16(ah, bl[ct][ks], acc[rt][ct], 0, 0, 0);
            }
        }
}
__device__ __forceinline__ void mfmaE_reg(f4 acc[4][2], const short* __restrict__ At, int sa,
                                          const s8 bh[2][4], const s8 bl[2][4], int nk, int lane) {
    const int r16 = lane & 15, q8 = (lane >> 4) * 8;
#pragma unroll 4
    for (int ks = 0; ks < nk; ++ks)
#pragma unroll
        for (int rt = 0; rt < 4; ++rt) {
            s8 a = *(const s8*)(At + (rt * 16 + r16) * sa + ks * 32 + q8);
#pragma unroll
            for (int ct = 0; ct < 2; ++ct) {
                acc[rt][ct] = __builtin_amdgcn_mfma_f32_16x16x32_bf16(a, bh[ct][ks], acc[rt][ct], 0, 0, 0);
                acc[rt][ct] = __builtin_amdgcn_mfma_f32_16x16x32_bf16(a, bl[ct][ks], acc[rt][ct], 0, 0, 0);
            }
        }
}
__device__ __forceinline__ void dumpC_half2(float* __restrict__ Cd, const f4 acc[4][2],
                                            int half, int w, int lane) {
    if ((w >> 1) != half) return;
    const int col0 = lane & 15, rq = (lane >> 4) * 4;
    const int bc = (w & 1) * 2;
#pragma unroll
    for (int rt = 0; rt < 4; ++rt)
#pragma unroll
        for (int ct = 0; ct < 2; ++ct)
#pragma unroll
            for (int r = 0; r < 4; ++r)
                Cd[(rt * 16 + rq + r) * SC2 + (bc + ct) * 16 + col0] = acc[rt][ct][r];
}
#define ACC_ZERO2(acc) { f4 z_ = {0.f, 0.f, 0.f, 0.f}; \
    for (int r_ = 0; r_ < 4; ++r_) for (int c_ = 0; c_ < 2; ++c_) acc[r_][c_] = z_; }

// ---------------------------------------------------------------------------
// dual GEMM (layer 0 only): Hs = h@W1a, Hd = h@W1b (bf16 out)
// ---------------------------------------------------------------------------
__global__ __launch_bounds__(256) void dual_k(const float* __restrict__ h,
                                              const unsigned short* __restrict__ W1aT,
                                              const unsigned short* __restrict__ W1bT,
                                              unsigned short* __restrict__ Hs, unsigned short* __restrict__ Hd,
                                              int M) {
    __shared__ __align__(16) short At[64 * SA];
    __shared__ __align__(16) short Al[64 * SA];
    __shared__ __align__(16) float Cd[64 * SC2];
    const int tid = threadIdx.x, lane = tid & 63, w = tid >> 6, tx = tid & 15, ty = tid >> 4;
    const int bm = blockIdx.x * 64;
    s8 bh[2][4], bl[2][4];
    loadB2(bh, W1aT, HD, 4, w, lane);
    loadB2(bl, W1aT + 16384, HD, 4, w, lane);
    stageA_f32_split(At, Al, h, bm, M, tid);
    __syncthreads();
    f4 acc[4][2]; ACC_ZERO2(acc);
    mfma3_reg(acc, At, Al, SA, bh, bl, 4, lane);
    loadB2(bh, W1bT, HD, 4, w, lane);
    loadB2(bl, W1bT + 16384, HD, 4, w, lane);
#pragma unroll
    for (int half = 0; half < 2; ++half) {
        __syncthreads();
        dumpC_half2(Cd, acc, half, w, lane);
        __syncthreads();
        int c4 = half * 64 + tx * 4;
#pragma unroll
        for (int i = 0; i < 4; ++i) {
            int row = ty * 4 + i, gr = bm + row;
            if (gr >= M) continue;
            f4 v = *(const f4*)(Cd + row * SC2 + tx * 4);
            us4 o;
#pragma unroll
            for (int j = 0; j < 4; ++j) o[j] = f2b(v[j]);
            *(us4*)(Hs + (long)gr * HD + c4) = o;
        }
    }
    ACC_ZERO2(acc);
    mfma3_reg(acc, At, Al, SA, bh, bl, 4, lane);
#pragma unroll
    for (int half = 0; half < 2; ++half) {
        __syncthreads();
        dumpC_half2(Cd, acc, half, w, lane);
        __syncthreads();
        int c4 = half * 64 + tx * 4;
#pragma unroll
        for (int i = 0; i < 4; ++i) {
            int row = ty * 4 + i, gr = bm + row;
            if (gr >= M) continue;
            f4 v = *(const f4*)(Cd + row * SC2 + tx * 4);
            us4 o;
#pragma unroll
            for (int j = 0; j < 4; ++j) o[j] = f2b(v[j]);
            *(us4*)(Hd + (long)gr * HD + c4) = o;
        }
    }
}

// ---------------------------------------------------------------------------
// edge: Pe[edge] = relu(eS@W1c + b1 + Hs[src] + Hd[dst])  (no atomics)
// ---------------------------------------------------------------------------
__global__ __launch_bounds__(256) void edge_k(const unsigned short* __restrict__ eS,
                                              const unsigned short* __restrict__ Hs,
                                              const unsigned short* __restrict__ Hd,
                                              const int* __restrict__ srcS, const int* __restrict__ dstS,
                                              const unsigned short* __restrict__ W1cT,
                                              const float* __restrict__ b1,
                                              unsigned short* __restrict__ Pe) {
    __shared__ __align__(16) short At[64 * SA];
    __shared__ __align__(16) float Cd[64 * SC2];
    const int tid = threadIdx.x, lane = tid & 63, w = tid >> 6, tx = tid & 15, ty = tid >> 4;
    const int bm = blockIdx.x * 64;
    s8 bh[2][4], bl[2][4];
    loadB2(bh, W1cT, HD, 4, w, lane);
    loadB2(bl, W1cT + 16384, HD, 4, w, lane);
    stageA_b16(At, eS, bm, NE, tid);
    __syncthreads();
    f4 acc[4][2]; ACC_ZERO2(acc);
    mfmaE_reg(acc, At, SA, bh, bl, 4, lane);
#pragma unroll
    for (int half = 0; half < 2; ++half) {
        __syncthreads();
        dumpC_half2(Cd, acc, half, w, lane);
        __syncthreads();
        int c4 = half * 64 + tx * 4;
        f4 bv = *(const f4*)(b1 + c4);
#pragma unroll
        for (int i = 0; i < 4; ++i) {
            int row = ty * 4 + i, edge = bm + row;
            int s = srcS[edge], d = dstS[edge];
            us4 hs = *(const us4*)(Hs + (long)s * HD + c4);
            us4 hd = *(const us4*)(Hd + (long)d * HD + c4);
            f4 cv = *(const f4*)(Cd + row * SC2 + tx * 4);
            us4 o;
#pragma unroll
            for (int j = 0; j < 4; ++j)
                o[j] = f2b(fmaxf(cv[j] + bv[j] + b2f(hs[j]) + b2f(hd[j]), 0.f));
            *(us4*)(Pe + (long)edge * HD + c4) = o;
        }
    }
}

// ---------------------------------------------------------------------------
// update (+fused next-layer dual): S = segsum(Pe); T = relu(h@uW1a + S@W2u +
// deg*b2u + ub1); h += T@uW2 + ub2; if W1aTn: Hs/Hd = h_new @ W1a'/W1b'
// ---------------------------------------------------------------------------
__global__ __launch_bounds__(256) void upd_k(float* __restrict__ h,
                                             const unsigned short* __restrict__ Pe,
                                             const int* __restrict__ rowp,
                                             const unsigned short* __restrict__ uW1aT,
                                             const unsigned short* __restrict__ W2uT,
                                             const float* __restrict__ ub1, const float* __restrict__ b2u,
                                             const float* __restrict__ deg,
                                             const unsigned short* __restrict__ uW2T,
                                             const float* __restrict__ ub2,
                                             const unsigned short* __restrict__ W1aTn,
                                             const unsigned short* __restrict__ W1bTn,
                                             unsigned short* __restrict__ Hs,
                                             unsigned short* __restrict__ Hd, int M) {
    __shared__ __align__(16) short At[64 * SA];
    __shared__ __align__(16) short Al[64 * SA];
    __shared__ __align__(16) float Cd[64 * SC2];
    const int tid = threadIdx.x, lane = tid & 63, w = tid >> 6, tx = tid & 15, ty = tid >> 4;
    const int bm = blockIdx.x * 64;
    s8 bh[2][4], bl[2][4];
    f4 acc[4][2]; ACC_ZERO2(acc);
    loadB2(bh, uW1aT, HD, 4, w, lane);
    loadB2(bl, uW1aT + 16384, HD, 4, w, lane);
    stageA_f32_split(At, Al, h, bm, M, tid);
    __syncthreads();
    mfma3_reg(acc, At, Al, SA, bh, bl, 4, lane);
    loadB2(bh, W2uT, HD, 4, w, lane);
    loadB2(bl, W2uT + 16384, HD, 4, w, lane);
    __syncthreads();
    stage_segsum_split(At, Al, Pe, rowp, bm, M, tid);
    __syncthreads();
    mfma3_reg(acc, At, Al, SA, bh, bl, 4, lane);
    loadB2(bh, uW2T, HD, 4, w, lane);
    loadB2(bl, uW2T + 16384, HD, 4, w, lane);
    __syncthreads();
    // T = relu(acc + ub1 + deg*b2u) -> At/Al (hi/lo); wave w owns cols 2w,2w+1
    {
        const int col0 = lane & 15, rq = (lane >> 4) * 4;
        float u1[2], u2[2];
#pragma unroll
        for (int ct = 0; ct < 2; ++ct) {
            int col = (2 * w + ct) * 16 + col0;
            u1[ct] = ub1[col]; u2[ct] = b2u[col];
        }
        float dgv[16];
#pragma unroll
        for (int rt = 0; rt < 4; ++rt)
#pragma unroll
            for (int r = 0; r < 4; ++r) {
                int gr = bm + rt * 16 + rq + r;
                dgv[rt * 4 + r] = (gr < M) ? deg[gr] : 0.f;
            }
#pragma unroll
        for (int rt = 0; rt < 4; ++rt)
#pragma unroll
            for (int ct = 0; ct < 2; ++ct)
#pragma unroll
                for (int r = 0; r < 4; ++r) {
                    float p = fmaxf(acc[rt][ct][r] + u1[ct] + dgv[rt * 4 + r] * u2[ct], 0.f);
                    hl2 pp = split2(p);
                    int off = (rt * 16 + rq + r) * SA + (2 * w + ct) * 16 + col0;
                    At[off] = pp.hi;
                    Al[off] = pp.lo;
                }
    }
    __syncthreads();
    ACC_ZERO2(acc);
    mfma3_reg(acc, At, Al, SA, bh, bl, 4, lane);
    __syncthreads();   // all waves done reading T from At/Al before overwrite below
#pragma unroll
    for (int half = 0; half < 2; ++half) {
        __syncthreads();
        dumpC_half2(Cd, acc, half, w, lane);
        __syncthreads();
        int c4 = half * 64 + tx * 4;
        f4 u0 = *(const f4*)(ub2 + c4);
#pragma unroll
        for (int i = 0; i < 4; ++i) {
            int row = ty * 4 + i, gr = bm + row;
            if (gr >= M) continue;
            float* hp = h + (long)gr * HD + c4;
            f4 a = *(f4*)hp;
            f4 cv = *(const f4*)(Cd + row * SC2 + tx * 4);
#pragma unroll
            for (int j = 0; j < 4; ++j) a[j] += cv[j] + u0[j];
            *(f4*)hp = a;
            // stash new h split into At/Al for fused next-layer dual
#pragma unroll
            for (int j = 0; j < 4; ++j) {
                hl2 pp = split2(a[j]);
                At[row * SA + c4 + j] = pp.hi;
                Al[row * SA + c4 + j] = pp.lo;
            }
        }
    }
    if (!W1aTn) return;
    // fused dual: Hs/Hd = h_new @ W1a'/W1b'
    loadB2(bh, W1aTn, HD, 4, w, lane);
    loadB2(bl, W1aTn + 16384, HD, 4, w, lane);
    __syncthreads();
    ACC_ZERO2(acc);
    mfma3_reg(acc, At, Al, SA, bh, bl, 4, lane);
    loadB2(bh, W1bTn, HD, 4, w, lane);
    loadB2(bl, W1bTn + 16384, HD, 4, w, lane);
#pragma unroll
    for (int half = 0; half < 2; ++half) {
        __syncthreads();
        dumpC_half2(Cd, acc, half, w, lane);
        __syncthreads();
        int c4 = half * 64 + tx * 4;
#pragma unroll
        for (int i = 0; i < 4; ++i) {
            int row = ty * 4 + i, gr = bm + row;
            if (gr >= M) continue;
            f4 v = *(const f4*)(Cd + row * SC2 + tx * 4);
            us4 o;
#pragma unroll
            for (int j = 0; j < 4; ++j) o[j] = f2b(v[j]);
            *(us4*)(Hs + (long)gr * HD + c4) = o;
        }
    }
    ACC_ZERO2(acc);
    mfma3_reg(acc, At, Al, SA, bh, bl, 4, lane);
#pragma unroll
    for (int half = 0; half < 2; ++half) {
        __syncthreads();
        dumpC_half2(Cd, acc, half, w, lane);
        __syncthreads();
        int c4 = half * 64 + tx * 4;
#pragma unroll
        for (int i = 0; i < 4; ++i) {
            int row = ty * 4 + i, gr = bm + row;
            if (gr >= M) continue;
            f4 v = *(const f4*)(Cd + row * SC2 + tx * 4);
            us4 o;
#pragma unroll
            for (int j = 0; j < 4; ++j) o[j] = f2b(v[j]);
            *(us4*)(Hd + (long)gr * HD + c4) = o;
        }
    }
}

// ---------------------------------------------------------------------------
// fused 2-layer encoder (split-precision MFMA). SCAT: bf16 scatter via pos.
// ---------------------------------------------------------------------------
template<bool SCAT>
__global__ __launch_bounds__(256) void enc_k(const float* __restrict__ A, int KIN,
                                             const unsigned short* __restrict__ W1T, const float* __restrict__ b1,
                                             const unsigned short* __restrict__ W2T, const float* __restrict__ b2,
                                             float* __restrict__ outF, unsigned short* __restrict__ outB,
                                             const int* __restrict__ pos, int M) {
    __shared__ __align__(16) short At[64 * SA];
    __shared__ __align__(16) short Al[64 * SA];
    __shared__ __align__(16) float Cd[64 * SC2];
    const int tid = threadIdx.x, lane = tid & 63, w = tid >> 6, tx = tid & 15, ty = tid >> 4;
    const int bm = blockIdx.x * 64;
    s8 bh[2][4], bl[2][4];
    loadB2(bh, W1T, 32, 1, w, lane);
    loadB2(bl, W1T + 4096, 32, 1, w, lane);
    {
        int row = tid >> 2, k8 = (tid & 3) * 8;
        int gr = bm + row;
        s8 vh = (s8)0, vl = (s8)0;
        if (gr < M) {
#pragma unroll
            for (int i = 0; i < 8; ++i) {
                int k = k8 + i;
                if (k < KIN) {
                    hl2 p = split2(A[(long)gr * KIN + k]);
                    vh[i] = p.hi; vl[i] = p.lo;
                }
            }
        }
        *(s8*)(At + row * SA32 + k8) = vh;
        *(s8*)(Al + row * SA32 + k8) = vl;
    }
    __syncthreads();
    f4 acc[4][2]; ACC_ZERO2(acc);
    mfma3_reg(acc, At, Al, SA32, bh, bl, 1, lane);
    loadB2(bh, W2T, HD, 4, w, lane);
    loadB2(bl, W2T + 16384, HD, 4, w, lane);
    __syncthreads();
    {
        const int col0 = lane & 15, rq = (lane >> 4) * 4;
        float bb[2];
#pragma unroll
        for (int ct = 0; ct < 2; ++ct) bb[ct] = b1[(2 * w + ct) * 16 + col0];
#pragma unroll
        for (int rt = 0; rt < 4; ++rt)
#pragma unroll
            for (int ct = 0; ct < 2; ++ct)
#pragma unroll
                for (int r = 0; r < 4; ++r) {
                    float p = fmaxf(acc[rt][ct][r] + bb[ct], 0.f);
                    hl2 pp = split2(p);
                    int off = (rt * 16 + rq + r) * SA + (2 * w + ct) * 16 + col0;
                    At[off] = pp.hi;
                    Al[off] = pp.lo;
                }
    }
    __syncthreads();
    ACC_ZERO2(acc);
    mfma3_reg(acc, At, Al, SA, bh, bl, 4, lane);
#pragma unroll
    for (int half = 0; half < 2; ++half) {
        __syncthreads();
        dumpC_half2(Cd, acc, half, w, lane);
        __syncthreads();
        int c4 = half * 64 + tx * 4;
        f4 bv = *(const f4*)(b2 + c4);
#pragma unroll
        for (int i = 0; i < 4; ++i) {
            int row = ty * 4 + i, gr = bm + row;
            if (gr >= M) continue;
            f4 cv = *(const f4*)(Cd + row * SC2 + tx * 4);
            if constexpr (SCAT) {
                int p = pos[gr];
                us4 o;
#pragma unroll
                for (int j = 0; j < 4; ++j) o[j] = f2b(cv[j] + bv[j]);
                *(us4*)(outB + (long)p * HD + c4) = o;
            } else {
                f4 o;
#pragma unroll
                for (int j = 0; j < 4; ++j) o[j] = cv[j] + bv[j];
                *(f4*)(outF + (long)gr * HD + c4) = o;
            }
        }
    }
}

// ---------------------------------------------------------------------------
// MFMA decoder: d1 = relu(h@W1+b1); d2 = relu(d1@W2+b2); pred = d2@W3+b3; BC
// ---------------------------------------------------------------------------
__global__ __launch_bounds__(256) void dec2_k(const float* __restrict__ h,
                                              const unsigned short* __restrict__ WtD,
                                              const float* __restrict__ b1, const float* __restrict__ b2,
                                              const float* __restrict__ W3, const float* __restrict__ b3,
                                              const float* __restrict__ bc_disp, const float* __restrict__ bc_rot,
                                              float* __restrict__ outp, int M) {
    __shared__ __align__(16) short At[64 * SA];
    __shared__ __align__(16) short Al[64 * SA];
    __shared__ __align__(16) float D2[64 * 65];
    const int tid = threadIdx.x, lane = tid & 63, w = tid >> 6;
    const int bm = blockIdx.x * 64;
    s8 bh[2][4], bl[2][4];
    loadB2(bh, WtD, HD, 4, w, lane);
    loadB2(bl, WtD + 16384, HD, 4, w, lane);
    stageA_f32_split(At, Al, h, bm, M, tid);
    __syncthreads();
    f4 acc[4][2]; ACC_ZERO2(acc);
    mfma3_reg(acc, At, Al, SA, bh, bl, 4, lane);
    __syncthreads();
    // P = relu(acc + b1) -> At/Al
    {
        const int col0 = lane & 15, rq = (lane >> 4) * 4;
        float bb[2];
#pragma unroll
        for (int ct = 0; ct < 2; ++ct) bb[ct] = b1[(2 * w + ct) * 16 + col0];
#pragma unroll
        for (int rt = 0; rt < 4; ++rt)
#pragma unroll
            for (int ct = 0; ct < 2; ++ct)
#pragma unroll
                for (int r = 0; r < 4; ++r) {
                    float p = fmaxf(acc[rt][ct][r] + bb[ct], 0.f);
                    hl2 pp = split2(p);
                    int off = (rt * 16 + rq + r) * SA + (2 * w + ct) * 16 + col0;
                    At[off] = pp.hi;
                    Al[off] = pp.lo;
                }
    }
    __syncthreads();
    // phase B: d2 = relu(P @ W2 + b2), 64 cols; wave w owns cols w*16..+15
    {
        const int r16 = lane & 15, q8 = (lane >> 4) * 8, rq = (lane >> 4) * 4;
        s8 b2h[4], b2l[4];
#pragma unroll
        for (int ks = 0; ks < 4; ++ks) {
            b2h[ks] = *(const s8*)((const short*)WtD + 32768 + (long)(w * 16 + r16) * HD + ks * 32 + q8);
            b2l[ks] = *(const s8*)((const short*)WtD + 40960 + (long)(w * 16 + r16) * HD + ks * 32 + q8);
        }
        f4 acc2[4];
        { f4 z_ = {0.f, 0.f, 0.f, 0.f}; for (int r_ = 0; r_ < 4; ++r_) acc2[r_] = z_; }
#pragma unroll
        for (int ks = 0; ks < 4; ++ks)
#pragma unroll
            for (int rt = 0; rt < 4; ++rt) {
                s8 ah = *(const s8*)(At + (rt * 16 + r16) * SA + ks * 32 + q8);
                s8 al = *(const s8*)(Al + (rt * 16 + r16) * SA + ks * 32 + q8);
                acc2[rt] = __builtin_amdgcn_mfma_f32_16x16x32_bf16(ah, b2h[ks], acc2[rt], 0, 0, 0);
                acc2[rt] = __builtin_amdgcn_mfma_f32_16x16x32_bf16(al, b2h[ks], acc2[rt], 0, 0, 0);
                acc2[rt] = __builtin_amdgcn_mfma_f32_16x16x32_bf16(ah, b2l[ks], acc2[rt], 0, 0, 0);
            }
        float b2v = b2[w * 16 + r16];
#pragma unroll
        for (int rt = 0; rt < 4; ++rt)
#pragma unroll
            for (int r = 0; r < 4; ++r)
                D2[(rt * 16 + rq + r) * 65 + w * 16 + r16] = fmaxf(acc2[rt][r] + b2v, 0.f);
    }
    __syncthreads();
    // phase C: pred = d2 @ W3 + b3, BC masks
    if (tid < 64) {
        int gr = bm + tid;
        if (gr < M) {
            float a0 = b3[0], a1 = b3[1], a2 = b3[2];
#pragma unroll
            for (int k = 0; k < 64; ++k) {
                float v = D2[tid * 65 + k];
                a0 = fmaf(v, W3[k * 3 + 0], a0);
                a1 = fmaf(v, W3[k * 3 + 1], a1);
                a2 = fmaf(v, W3[k * 3 + 2], a2);
            }
            outp[gr * 3 + 0] = a0 * (1.f - bc_disp[gr * 2 + 0]);
            outp[gr * 3 + 1] = a1 * (1.f - bc_disp[gr * 2 + 1]);
            outp[gr * 3 + 2] = a2 * (1.f - bc_rot[gr]);
        }
    }
}

// ---------------------------------------------------------------------------
extern "C" void kernel_launch(void* const* d_in, const int* in_sizes, int n_in,
                              void* d_out, int out_size, void* d_ws, size_t ws_size,
                              hipStream_t stream)
{
    const float* x        = (const float*)d_in[0];
    const float* eattr    = (const float*)d_in[1];
    const int*   eidx     = (const int*)d_in[2];
    const float* bc_disp  = (const float*)d_in[3];
    const float* bc_rot   = (const float*)d_in[4];
    const float* enc_n_W1 = (const float*)d_in[5];
    const float* enc_n_b1 = (const float*)d_in[6];
    const float* enc_n_W2 = (const float*)d_in[7];
    const float* enc_n_b2 = (const float*)d_in[8];
    const float* enc_e_W1 = (const float*)d_in[9];
    const float* enc_e_b1 = (const float*)d_in[10];
    const float* enc_e_W2 = (const float*)d_in[11];
    const float* enc_e_b2 = (const float*)d_in[12];
    const float* msg_W1   = (const float*)d_in[13];
    const float* msg_b1   = (const float*)d_in[14];
    const float* msg_W2   = (const float*)d_in[15];
    const float* msg_b2   = (const float*)d_in[16];
    const float* upd_W1   = (const float*)d_in[17];
    const float* upd_b1   = (const float*)d_in[18];
    const float* upd_W2   = (const float*)d_in[19];
    const float* upd_b2   = (const float*)d_in[20];
    const float* dec_W1   = (const float*)d_in[21];
    const float* dec_b1   = (const float*)d_in[22];
    const float* dec_W2   = (const float*)d_in[23];
    const float* dec_b2   = (const float*)d_in[24];
    const float* dec_W3   = (const float*)d_in[25];
    const float* dec_b3   = (const float*)d_in[26];

    const int* src = eidx;
    const int* dst = eidx + NE;

    // workspace layout
    char* base = (char*)d_ws;
    float* h  = (float*)base;                                   // NN*HD f32
    unsigned short* Hs = (unsigned short*)(h + (long)NN * HD);  // NN*HD bf16
    unsigned short* Hd = Hs + (long)NN * HD;                    // NN*HD bf16
    unsigned short* eS = Hd + (long)NN * HD;                    // NE*HD bf16
    unsigned short* Pe = eS + (long)NE * HD;                    // NE*HD bf16
    float* W2uF = (float*)(Pe + (long)NE * HD);                 // 6*128*128 f32
    float* b2uA = W2uF + 6 * HD * HD;                           // 6*128 f32
    unsigned short* WtL = (unsigned short*)(b2uA + 6 * HD);     // 6*6*32768 bf16
    unsigned short* WtE = WtL + 6L * 6 * 32768;                 // 81920 bf16
    unsigned short* WtD = WtE + 81920;                          // 49152 bf16
    float* deg = (float*)(WtD + 49152);                         // NN f32
    int* rowp  = (int*)(deg + NN);                              // NN+1
    int* cnt   = rowp + (NN + 1);                               // NN
    int* posb  = cnt + NN;                                      // NE
    int* srcS  = posb + NE;                                     // NE
    int* dstS  = srcS + NE;                                     // NE
    int* bsum  = dstS + NE;                                     // 256
    size_t need = (size_t)((char*)(bsum + 256) - base);
    if (ws_size < need) {
        zerof_k<<<(unsigned)((out_size + 255) / 256), 256, 0, stream>>>((float*)d_out, out_size);
        return;
    }

    dim3 blk(256);
    const unsigned gN  = (NN + 63) / 64;    // 782
    const unsigned gE  = NE / 64;           // 3125
    const unsigned gNc = (NN + 255) / 256;  // 196
    const unsigned gEc = (NE + 255) / 256;  // 782

    // --- prologue: counting sort of edges by dst ---
    zeroi_k<<<gNc, blk, 0, stream>>>(cnt, NN);
    hist_k<<<gEc, blk, 0, stream>>>(dst, cnt);
    scan1_k<<<gNc, blk, 0, stream>>>(cnt, bsum);
    scan2_k<<<1, blk, 0, stream>>>(bsum, (int)gNc);
    scan3_k<<<gNc, blk, 0, stream>>>(cnt, bsum, rowp, deg);
    zeroi_k<<<gNc, blk, 0, stream>>>(cnt, NN);
    posbuild_k<<<gEc, blk, 0, stream>>>(src, dst, rowp, cnt, posb, srcS, dstS);

    // --- weight prep ---
    for (int l = 0; l < 6; ++l) {
        mini_k<<<8, blk, 0, stream>>>(msg_W2 + (long)l * HD * HD,
                                      upd_W1 + (long)l * 256 * HD + 128 * HD,
                                      msg_b2 + (long)l * HD,
                                      W2uF + (long)l * HD * HD, b2uA + (long)l * HD);
    }
    for (int l = 0; l < 6; ++l) {
        wtL_k<<<384, blk, 0, stream>>>(msg_W1 + (long)l * 384 * HD,
                                       upd_W1 + (long)l * 256 * HD,
                                       upd_W2 + (long)l * HD * HD,
                                       W2uF + (long)l * HD * HD,
                                       WtL + (long)l * 6 * 32768);
    }
    wtE_k<<<160, blk, 0, stream>>>(enc_n_W1, enc_n_W2, enc_e_W1, enc_e_W2, WtE);
    wtD_k<<<96, blk, 0, stream>>>(dec_W1, dec_W2, WtD);

    // --- encoders ---
    enc_k<false><<<gN, blk, 0, stream>>>(x, 9, WtE, enc_n_b1, WtE + 8192, enc_n_b2,
                                         h, nullptr, nullptr, NN);
    enc_k<true><<<gE, blk, 0, stream>>>(eattr, 10, WtE + 40960, enc_e_b1, WtE + 49152, enc_e_b2,
                                        nullptr, eS, posb, NE);

    // --- message-passing layers (dual fused into previous upd; layer 0 standalone) ---
    dual_k<<<gN, blk, 0, stream>>>(h, WtL + 0L * 32768, WtL + 1L * 32768, Hs, Hd, NN);
    for (int l = 0; l < 6; ++l) {
        const unsigned short* Wt = WtL + (long)l * 6 * 32768;
        const float* b1  = msg_b1 + (long)l * HD;
        const float* ub1 = upd_b1 + (long)l * HD;
        const float* ub2 = upd_b2 + (long)l * HD;
        const float* b2u = b2uA + (long)l * HD;
        const unsigned short* Wn = (l < 5) ? (WtL + (long)(l + 1) * 6 * 32768) : nullptr;

        edge_k<<<gE, blk, 0, stream>>>(eS, Hs, Hd, srcS, dstS, Wt + 2L * 32768, b1, Pe);
        upd_k<<<gN, blk, 0, stream>>>(h, Pe, rowp, Wt + 3L * 32768, Wt + 5L * 32768,
                                      ub1, b2u, deg, Wt + 4L * 32768, ub2,
                                      Wn, Wn ? (Wn + 32768) : nullptr, Hs, Hd, NN);
    }

    // --- decoder (MFMA) ---
    dec2_k<<<gN, blk, 0, stream>>>(h, WtD, dec_b1, dec_b2, dec_W3, dec_b3,
                                   bc_disp, bc_rot, (float*)d_out, NN);
}